// Round 4
// baseline (2016.167 us; speedup 1.0000x reference)
//
#include <hip/hip_runtime.h>

#define Hn 2048
#define Bn 8
#define Tn 2048
#define Cn 16
#define NCn (Tn / Cn)     // 128 chunks
#define M2n (NCn * Bn)    // 1024 scan rows

using f32x4 = __attribute__((ext_vector_type(4))) float;
using u32x4 = __attribute__((ext_vector_type(4))) unsigned int;
using us4   = __attribute__((ext_vector_type(4))) unsigned short;
using bf8   = __attribute__((ext_vector_type(8))) short;
using f4    = __attribute__((ext_vector_type(4))) float;

__device__ __forceinline__ unsigned short f2bf(float f) {
    unsigned u = __builtin_bit_cast(unsigned, f);
    u = u + 0x7fffu + ((u >> 16) & 1u);
    return (unsigned short)(u >> 16);
}
__device__ __forceinline__ float bf2f(unsigned short h) {
    unsigned u = ((unsigned)h) << 16;
    return __builtin_bit_cast(float, u);
}
__device__ __forceinline__ void split2f(float v, unsigned short& a, unsigned short& b) {
    a = f2bf(v);
    b = f2bf(v - bf2f(a));
}

// ---------------------------------------------------------------------------
// K0: canonicalize reset, firstReset/cut/anyUncut, counting-sort rows by
//     firstReset DESC -> perm/iperm/counts (alive prefix per correction step).
// ---------------------------------------------------------------------------
__global__ __launch_bounds__(256) void k_reset_prep(const unsigned int* __restrict__ rin,
                                                    unsigned char* __restrict__ r8,
                                                    int* __restrict__ cut,
                                                    int* __restrict__ firstReset,
                                                    int* __restrict__ anyUncut,
                                                    int* __restrict__ perm,
                                                    int* __restrict__ iperm,
                                                    int* __restrict__ counts) {
    __shared__ int s_badInt, s_badFloat;
    __shared__ int hist[17], off[18], cur[17];
    if (threadIdx.x == 0) { s_badInt = 0; s_badFloat = 0; *anyUncut = 0; }
    if (threadIdx.x < 17) hist[threadIdx.x] = 0;
    __syncthreads();
    int badI = 0, badF = 0;
    for (int i = threadIdx.x; i < 4096; i += 256) {
        unsigned int v = rin[i];
        if (v > 1u) badI = 1;
        if (v != 0u && v != 0x3f800000u) badF = 1;
    }
    if (badI) atomicOr(&s_badInt, 1);
    if (badF) atomicOr(&s_badFloat, 1);
    __syncthreads();
    const int fmt = (!s_badInt) ? 0 : ((!s_badFloat) ? 1 : 2);
    const unsigned char* rb = (const unsigned char*)rin;
    const float* rf = (const float*)rin;
    for (int i = threadIdx.x; i < Bn * Tn; i += 256) {
        unsigned char v;
        if (fmt == 0)      v = (unsigned char)(rin[i] != 0u);
        else if (fmt == 1) v = (unsigned char)(rf[i] != 0.0f);
        else               v = (unsigned char)(rb[i] != 0);
        r8[i] = v;
    }
    __syncthreads();
    int anyU = 0;
    for (int m = threadIdx.x; m < M2n; m += 256) {
        int c = m / Bn, b = m % Bn;
        int fr = Cn;
        for (int j = 0; j < Cn; j++) {
            if (r8[b * Tn + c * Cn + j]) { fr = j; break; }
        }
        firstReset[m] = fr;
        int ct = (fr < Cn);
        cut[m] = ct;
        if (!ct && c < NCn - 1) anyU = 1;
        atomicAdd(&hist[fr], 1);
    }
    if (anyU) atomicOr(anyUncut, 1);
    __syncthreads();
    if (threadIdx.x == 0) {
        off[16] = 0;
        for (int v = 15; v >= 0; v--) off[v] = off[v + 1] + hist[v + 1];
        for (int v = 0; v < 17; v++) cur[v] = (v == 16) ? 0 : off[v];
        for (int j = 0; j < 16; j++) counts[j] = off[j];
    }
    __syncthreads();
    for (int m = threadIdx.x; m < M2n; m += 256) {
        int fr = firstReset[m];
        int pos = atomicAdd(&cur[fr], 1);
        perm[pos] = m;
        iperm[m] = pos;
    }
}

// ---------------------------------------------------------------------------
// Split pre-passes (2-way hi/lo)
// ---------------------------------------------------------------------------
__global__ __launch_bounds__(256) void k_split_A2(const float* __restrict__ A,
                                                  unsigned short* __restrict__ a1,
                                                  unsigned short* __restrict__ a2) {
    size_t i = ((size_t)blockIdx.x * 256 + threadIdx.x) * 4;
    f32x4 v = *(const f32x4*)&A[i];
    us4 h1, h2;
#pragma unroll
    for (int e = 0; e < 4; e++) {
        unsigned short x1, x2;
        split2f(v[e], x1, x2);
        h1[e] = x1; h2[e] = x2;
    }
    *(us4*)&a1[i] = h1; *(us4*)&a2[i] = h2;
}

__global__ __launch_bounds__(256) void k_split_Bt(const float* __restrict__ Bm,
                                                  unsigned short* __restrict__ b1,
                                                  unsigned short* __restrict__ b2) {
    __shared__ float tile[64][65];
    const int k0 = blockIdx.y * 64, n0 = blockIdx.x * 64;
    const int c = threadIdx.x & 63, r4 = threadIdx.x >> 6;
#pragma unroll
    for (int i = 0; i < 16; i++) {
        int r = r4 * 16 + i;
        tile[r][c] = Bm[(size_t)(k0 + r) * Hn + n0 + c];
    }
    __syncthreads();
#pragma unroll
    for (int i = 0; i < 16; i++) {
        int r = r4 * 16 + i;
        float v = tile[c][r];                 // Bm[k0+c][n0+r]
        unsigned short x1, x2;
        split2f(v, x1, x2);
        b1[(size_t)(n0 + r) * Hn + k0 + c] = x1;
        b2[(size_t)(n0 + r) * Hn + k0 + c] = x2;
    }
}

__global__ __launch_bounds__(256) void k_split_X(const float* __restrict__ X,
                                                 unsigned short* __restrict__ x1,
                                                 unsigned short* __restrict__ x2) {
    size_t i = ((size_t)blockIdx.x * 256 + threadIdx.x) * 4;
    f32x4 v = *(const f32x4*)&X[i];
    us4 h1, h2;
#pragma unroll
    for (int e = 0; e < 4; e++) {
        unsigned short a, b;
        split2f(v[e], a, b);
        h1[e] = a; h2[e] = b;
    }
    *(us4*)&x1[i] = h1; *(us4*)&x2[i] = h2;
}

// ---------------------------------------------------------------------------
// Phase-1 GEMM: Out[m,n] = sum_k X[m,k]*Bt[n,k], 3 products.
// 256x128 tile, 512 threads (8 waves, 4m x 2n), FM=FN=4, BK=32.
// PREX=1: A-operand from pre-split x1/x2. PREX=0: inline split of fp32 X.
// ---------------------------------------------------------------------------
template<int PREX>
__global__ __launch_bounds__(512) void k_gemm_p1(const unsigned short* __restrict__ X0,
                                                 const unsigned short* __restrict__ X1,
                                                 const unsigned short* __restrict__ B0,
                                                 const unsigned short* __restrict__ B1,
                                                 const float* __restrict__ Xf,
                                                 float* __restrict__ Out) {
    constexpr int BM = 256, BN = 128, LW = 40;
    __shared__ unsigned short ldsA[2 * BM * LW];
    __shared__ unsigned short ldsB[2 * BN * LW];
    const int tid = threadIdx.x;
    const int lane = tid & 63;
    const int wv = tid >> 6;
    const int wm = wv >> 1, wn = wv & 1;     // 4m x 2n wave grid
    const int n0 = blockIdx.x * BN;
    const int m0 = blockIdx.y * BM;

    f4 acc[4][4];
#pragma unroll
    for (int fm = 0; fm < 4; fm++)
#pragma unroll
        for (int fn = 0; fn < 4; fn++) acc[fm][fn] = (f4){0.f, 0.f, 0.f, 0.f};

    // staging bases (hoisted)
    const unsigned short* gA[4];
    unsigned short* lA[4];
    const float* gX[2];
    unsigned short* lX[2];
    const unsigned short* gB[2];
    unsigned short* lB[2];
    if constexpr (PREX) {
#pragma unroll
        for (int q = 0; q < 4; q++) {
            int u = tid + q * 512;                 // 2048 items
            int sp = u >> 10, row = (u >> 2) & 255, slot = u & 3;
            gA[q] = (sp ? X1 : X0) + (size_t)(m0 + row) * Hn + slot * 8;
            lA[q] = &ldsA[(sp * BM + row) * LW + slot * 8];
        }
    } else {
#pragma unroll
        for (int q = 0; q < 2; q++) {
            int u = tid + q * 512;                 // 1024 items: row x slot(8 floats)
            int row = u >> 2, slot = u & 3;
            gX[q] = Xf + (size_t)(m0 + row) * Hn + slot * 8;
            lX[q] = &ldsA[row * LW + slot * 8];    // hi at sp=0; lo at +BM*LW
        }
    }
#pragma unroll
    for (int q = 0; q < 2; q++) {
        int u = tid + q * 512;                     // 1024 items
        int sp = u >> 9, row = (u >> 2) & 127, slot = u & 3;
        gB[q] = (sp ? B1 : B0) + (size_t)(n0 + row) * Hn + slot * 8;
        lB[q] = &ldsB[(sp * BN + row) * LW + slot * 8];
    }

    for (int k0 = 0; k0 < Hn; k0 += 32) {
        __syncthreads();
        if constexpr (PREX) {
#pragma unroll
            for (int q = 0; q < 4; q++) {
                *(u32x4*)lA[q] = *(const u32x4*)gA[q];
                gA[q] += 32;
            }
        } else {
#pragma unroll
            for (int q = 0; q < 2; q++) {
                f32x4 va = *(const f32x4*)gX[q];
                f32x4 vb = *(const f32x4*)(gX[q] + 4);
                gX[q] += 32;
                us4 h1a, h2a, h1b, h2b;
#pragma unroll
                for (int e = 0; e < 4; e++) {
                    unsigned short p, r;
                    split2f(va[e], p, r); h1a[e] = p; h2a[e] = r;
                    split2f(vb[e], p, r); h1b[e] = p; h2b[e] = r;
                }
                *(us4*)lX[q] = h1a;
                *(us4*)(lX[q] + 4) = h1b;
                *(us4*)(lX[q] + BM * LW) = h2a;
                *(us4*)(lX[q] + BM * LW + 4) = h2b;
            }
        }
#pragma unroll
        for (int q = 0; q < 2; q++) {
            *(u32x4*)lB[q] = *(const u32x4*)gB[q];
            gB[q] += 32;
        }
        __syncthreads();

        bf8 af[2][4], bfr[2][4];
#pragma unroll
        for (int sp = 0; sp < 2; sp++)
#pragma unroll
            for (int f = 0; f < 4; f++)
                af[sp][f] = *(const bf8*)&ldsA[(sp * BM + wm * 64 + f * 16 + (lane & 15)) * LW + (lane >> 4) * 8];
#pragma unroll
        for (int sp = 0; sp < 2; sp++)
#pragma unroll
            for (int f = 0; f < 4; f++)
                bfr[sp][f] = *(const bf8*)&ldsB[(sp * BN + wn * 64 + f * 16 + (lane & 15)) * LW + (lane >> 4) * 8];

        const int pa[3] = {0, 0, 1};
        const int pb[3] = {0, 1, 0};
#pragma unroll
        for (int p = 0; p < 3; p++)
#pragma unroll
            for (int fm = 0; fm < 4; fm++)
#pragma unroll
                for (int fn = 0; fn < 4; fn++)
                    acc[fm][fn] = __builtin_amdgcn_mfma_f32_16x16x32_bf16(
                        af[pa[p]][fm], bfr[pb[p]][fn], acc[fm][fn], 0, 0, 0);
    }

    // D mapping: row=(lane>>4)*4+r, col=lane&15
#pragma unroll
    for (int fm = 0; fm < 4; fm++)
#pragma unroll
        for (int r = 0; r < 4; r++) {
            int row = m0 + wm * 64 + fm * 16 + (lane >> 4) * 4 + r;
            size_t ob = (size_t)row * Hn;
#pragma unroll
            for (int fn = 0; fn < 4; fn++) {
                int n = n0 + wn * 64 + fn * 16 + (lane & 15);
                Out[ob + n] = acc[fm][fn][r];
            }
        }
}

// ---------------------------------------------------------------------------
// Scan / correction GEMM: 64x128 tile, 256 threads (2x2 waves), FM=2 FN=4.
// PHASE 2: v=(reset?0:acc)+Out; Out=v; split2 -> state (by m).
// PHASE 4: sorted alive prefix; split2 -> state (by s); Out += val.
// ---------------------------------------------------------------------------
template<int PHASE>
__global__ __launch_bounds__(256) void k_gemm_s(const unsigned short* __restrict__ S0,
                                                const unsigned short* __restrict__ S1,
                                                const unsigned short* __restrict__ W0,
                                                const unsigned short* __restrict__ W1,
                                                float* __restrict__ Out,
                                                unsigned short* __restrict__ O0,
                                                unsigned short* __restrict__ O1,
                                                const unsigned char* __restrict__ r8v,
                                                const int* __restrict__ perm,
                                                const int* __restrict__ counts,
                                                int j) {
    constexpr int BM = 64, BN = 128, LW = 40;
    __shared__ unsigned short ldsA[2 * BM * LW];
    __shared__ unsigned short ldsB[2 * BN * LW];
    const int tid = threadIdx.x;
    const int lane = tid & 63;
    const int wv = tid >> 6;
    const int wm = wv >> 1, wn = wv & 1;     // 2x2 wave grid
    const int n0 = blockIdx.x * BN;
    const int m0 = blockIdx.y * BM;

    int cnt = 0;
    if constexpr (PHASE == 4) {
        cnt = counts[j];
        if (m0 >= cnt) return;
    }

    f4 acc[2][4];
#pragma unroll
    for (int fm = 0; fm < 2; fm++)
#pragma unroll
        for (int fn = 0; fn < 4; fn++) acc[fm][fn] = (f4){0.f, 0.f, 0.f, 0.f};

    const unsigned short* gA[2];
    unsigned short* lA[2];
    const unsigned short* gB[4];
    unsigned short* lB[4];
#pragma unroll
    for (int q = 0; q < 2; q++) {
        int u = tid + q * 256;                     // 512 items
        int sp = u >> 8, row = (u >> 2) & 63, slot = u & 3;
        gA[q] = (sp ? S1 : S0) + (size_t)(m0 + row) * Hn + slot * 8;
        lA[q] = &ldsA[(sp * BM + row) * LW + slot * 8];
    }
#pragma unroll
    for (int q = 0; q < 4; q++) {
        int u = tid + q * 256;                     // 1024 items
        int sp = u >> 9, row = (u >> 2) & 127, slot = u & 3;
        gB[q] = (sp ? W1 : W0) + (size_t)(n0 + row) * Hn + slot * 8;
        lB[q] = &ldsB[(sp * BN + row) * LW + slot * 8];
    }

    for (int k0 = 0; k0 < Hn; k0 += 32) {
        __syncthreads();
#pragma unroll
        for (int q = 0; q < 2; q++) {
            *(u32x4*)lA[q] = *(const u32x4*)gA[q];
            gA[q] += 32;
        }
#pragma unroll
        for (int q = 0; q < 4; q++) {
            *(u32x4*)lB[q] = *(const u32x4*)gB[q];
            gB[q] += 32;
        }
        __syncthreads();

        bf8 af[2][2], bfr[2][4];
#pragma unroll
        for (int sp = 0; sp < 2; sp++)
#pragma unroll
            for (int f = 0; f < 2; f++)
                af[sp][f] = *(const bf8*)&ldsA[(sp * BM + wm * 32 + f * 16 + (lane & 15)) * LW + (lane >> 4) * 8];
#pragma unroll
        for (int sp = 0; sp < 2; sp++)
#pragma unroll
            for (int f = 0; f < 4; f++)
                bfr[sp][f] = *(const bf8*)&ldsB[(sp * BN + wn * 64 + f * 16 + (lane & 15)) * LW + (lane >> 4) * 8];

        const int pa[3] = {0, 0, 1};
        const int pb[3] = {0, 1, 0};
#pragma unroll
        for (int p = 0; p < 3; p++)
#pragma unroll
            for (int fm = 0; fm < 2; fm++)
#pragma unroll
                for (int fn = 0; fn < 4; fn++)
                    acc[fm][fn] = __builtin_amdgcn_mfma_f32_16x16x32_bf16(
                        af[pa[p]][fm], bfr[pb[p]][fn], acc[fm][fn], 0, 0, 0);
    }

    if constexpr (PHASE == 2) {
#pragma unroll
        for (int fm = 0; fm < 2; fm++)
#pragma unroll
            for (int r = 0; r < 4; r++) {
                int m = m0 + wm * 32 + fm * 16 + (lane >> 4) * 4 + r;
                int cch = m >> 3, bb = m & 7;
                int t = cch * Cn + j;
                int rfl = r8v[bb * Tn + t];
                size_t ob = ((size_t)bb * Tn + t) * (size_t)Hn;
                size_t sb = (size_t)m * Hn;
#pragma unroll
                for (int fn = 0; fn < 4; fn++) {
                    int n = n0 + wn * 64 + fn * 16 + (lane & 15);
                    float v = (rfl ? 0.0f : acc[fm][fn][r]) + Out[ob + n];
                    Out[ob + n] = v;
                    unsigned short h1, h2;
                    split2f(v, h1, h2);
                    O0[sb + n] = h1; O1[sb + n] = h2;
                }
            }
    } else {  // PHASE 4 (sorted prefix)
#pragma unroll
        for (int fm = 0; fm < 2; fm++)
#pragma unroll
            for (int r = 0; r < 4; r++) {
                int s = m0 + wm * 32 + fm * 16 + (lane >> 4) * 4 + r;
                int alive = (s < cnt);
                int m = perm[s];
                int cch = m >> 3, bb = m & 7;
                int t = cch * Cn + j;
                size_t ob = ((size_t)bb * Tn + t) * (size_t)Hn;
                size_t sb = (size_t)s * Hn;
#pragma unroll
                for (int fn = 0; fn < 4; fn++) {
                    int n = n0 + wn * 64 + fn * 16 + (lane & 15);
                    if (alive) {
                        float val = acc[fm][fn][r];
                        unsigned short h1, h2;
                        split2f(val, h1, h2);
                        O0[sb + n] = h1; O1[sb + n] = h2;
                        Out[ob + n] += val;
                    }
                }
            }
    }
}

// ---------------------------------------------------------------------------
// Scan step j=0: state = bx slice, split2.
// ---------------------------------------------------------------------------
__global__ __launch_bounds__(256) void k_step0(const float* __restrict__ Out,
                                               unsigned short* __restrict__ s1,
                                               unsigned short* __restrict__ s2) {
    int i = blockIdx.x * 256 + threadIdx.x;
    int m = i >> 9;
    int nq = (i & 511) * 4;
    int c = m >> 3, b = m & 7;
    f32x4 v = *(const f32x4*)&Out[((size_t)b * Tn + c * Cn) * Hn + nq];
    us4 h1, h2;
#pragma unroll
    for (int e = 0; e < 4; e++) {
        unsigned short x1, x2;
        split2f(v[e], x1, x2);
        h1[e] = x1; h2[e] = x2;
    }
    size_t o = (size_t)m * Hn + nq;
    *(us4*)&s1[o] = h1; *(us4*)&s2[o] = h2;
}

// ---------------------------------------------------------------------------
// Carry-in: sorted u_0 splits + fp32 Hin (orig order, for fallback).
// ---------------------------------------------------------------------------
__global__ __launch_bounds__(256) void k_hin_split(const float* __restrict__ Out,
                                                   float* __restrict__ Hin,
                                                   unsigned short* __restrict__ u1,
                                                   unsigned short* __restrict__ u2,
                                                   const int* __restrict__ perm) {
    int i = blockIdx.x * 256 + threadIdx.x;
    int s = i >> 9;
    int nq = (i & 511) * 4;
    int m = perm[s];
    int c = m >> 3, b = m & 7;
    f32x4 v = {0.f, 0.f, 0.f, 0.f};
    if (c) v = *(const f32x4*)&Out[((size_t)b * Tn + (size_t)c * Cn - 1) * Hn + nq];
    *(f32x4*)&Hin[(size_t)m * Hn + nq] = v;
    us4 h1, h2;
#pragma unroll
    for (int e = 0; e < 4; e++) {
        unsigned short x1, x2;
        split2f(v[e], x1, x2);
        h1[e] = x1; h2[e] = x2;
    }
    size_t o = (size_t)s * Hn + nq;
    *(us4*)&u1[o] = h1; *(us4*)&u2[o] = h2;
}

// ---------------------------------------------------------------------------
// Exact fallback for uncut chunks (E[occurrences] ~ 0.016).
// ---------------------------------------------------------------------------
__global__ __launch_bounds__(1024) void k_fallback(float* __restrict__ Hin,
                                                   const float* __restrict__ A,
                                                   const int* __restrict__ cut,
                                                   const int* __restrict__ anyUncut,
                                                   unsigned short* __restrict__ u1,
                                                   unsigned short* __restrict__ u2,
                                                   const int* __restrict__ iperm) {
    if (*anyUncut == 0) return;
    __shared__ float v0[Hn];
    __shared__ float v1[Hn];
    for (int c = 1; c < NCn; c++) {
        for (int b = 0; b < Bn; b++) {
            if (cut[(c - 1) * Bn + b]) continue;
            for (int n = threadIdx.x; n < Hn; n += 1024)
                v0[n] = Hin[((size_t)(c - 1) * Bn + b) * Hn + n];
            __syncthreads();
            for (int s = 0; s < Cn; s++) {
                float* pin = (s & 1) ? v1 : v0;
                float* pout = (s & 1) ? v0 : v1;
                for (int n = threadIdx.x; n < Hn; n += 1024) {
                    float accv = 0.0f;
                    const float* Ar = &A[(size_t)n * Hn];
                    for (int k = 0; k < Hn; k++) accv += pin[k] * Ar[k];
                    pout[n] = accv;
                }
                __syncthreads();
            }
            float* pres = (Cn & 1) ? v1 : v0;
            int mrow = c * Bn + b;
            size_t dst = (size_t)mrow * Hn;
            size_t sdst = (size_t)iperm[mrow] * Hn;
            for (int n = threadIdx.x; n < Hn; n += 1024) {
                float nv = Hin[dst + n] + pres[n];
                Hin[dst + n] = nv;
                unsigned short h1, h2;
                split2f(nv, h1, h2);
                u1[sdst + n] = h1; u2[sdst + n] = h2;
            }
            __syncthreads();
        }
    }
}

extern "C" void kernel_launch(void* const* d_in, const int* in_sizes, int n_in,
                              void* d_out, int out_size, void* d_ws, size_t ws_size,
                              hipStream_t stream) {
    const float* x = (const float*)d_in[0];
    const unsigned int* rst = (const unsigned int*)d_in[1];
    const float* Am = (const float*)d_in[2];
    const float* Bm = (const float*)d_in[3];
    float* Out = (float*)d_out;
    char* ws = (char*)d_ws;

    unsigned char* r8 = (unsigned char*)ws;                 // 16 KB
    int* cut = (int*)(ws + 16384);
    int* firstReset = (int*)(ws + 20480);
    int* perm = (int*)(ws + 24576);
    int* iperm = (int*)(ws + 28672);
    int* counts = (int*)(ws + 32768);
    int* anyUncut = (int*)(ws + 32832);
    unsigned short* a1 = (unsigned short*)(ws + 65536);     // A splits [n][k], 8MB ea
    unsigned short* a2 = a1 + 4194304;
    unsigned short* b1 = a2 + 4194304;                      // Bt splits [n][k], 8MB ea
    unsigned short* b2 = b1 + 4194304;
    unsigned short* sP1 = b2 + 4194304;                     // state/u splits, 4MB ea
    unsigned short* sP2 = sP1 + 2097152;
    unsigned short* sQ1 = sP2 + 2097152;
    unsigned short* sQ2 = sQ1 + 2097152;
    float* Hin = (float*)(sQ2 + 2097152);                   // 8MB fp32
    unsigned short* x1 = (unsigned short*)(Hin + 2097152);  // X splits, 67MB ea
    unsigned short* x2 = x1 + 33554432;
    const size_t NEED_X = 193003520ull;
    const bool prex = (ws_size >= NEED_X);

    k_reset_prep<<<1, 256, 0, stream>>>(rst, r8, cut, firstReset, anyUncut, perm, iperm, counts);
    k_split_A2<<<4096, 256, 0, stream>>>(Am, a1, a2);
    k_split_Bt<<<dim3(32, 32), 256, 0, stream>>>(Bm, b1, b2);

    // Phase 1: bx = x @ B  (256x128 tile, FM=FN=4)
    if (prex) {
        k_split_X<<<32768, 256, 0, stream>>>(x, x1, x2);
        k_gemm_p1<1><<<dim3(Hn / 128, (Bn * Tn) / 256), 512, 0, stream>>>(
            x1, x2, b1, b2, nullptr, Out);
    } else {
        k_gemm_p1<0><<<dim3(Hn / 128, (Bn * Tn) / 256), 512, 0, stream>>>(
            nullptr, nullptr, b1, b2, x, Out);
    }

    // Phase 2: chunk-local scans
    k_step0<<<2048, 256, 0, stream>>>(Out, sP1, sP2);
    for (int j = 1; j < Cn; j++) {
        const unsigned short* i1 = (j & 1) ? sP1 : sQ1;
        const unsigned short* i2 = (j & 1) ? sP2 : sQ2;
        unsigned short* o1 = (j & 1) ? sQ1 : sP1;
        unsigned short* o2 = (j & 1) ? sQ2 : sP2;
        k_gemm_s<2><<<dim3(Hn / 128, M2n / 64), 256, 0, stream>>>(
            i1, i2, a1, a2, Out, o1, o2, r8, nullptr, nullptr, j);
    }

    // Phase 3: carry-in (sorted) + exact fallback
    k_hin_split<<<2048, 256, 0, stream>>>(Out, Hin, sP1, sP2, perm);
    k_fallback<<<1, 1024, 0, stream>>>(Hin, Am, cut, anyUncut, sP1, sP2, iperm);

    // Phase 4: corrections on shrinking sorted prefix
    for (int j = 0; j < Cn; j++) {
        const unsigned short* i1 = (j & 1) ? sQ1 : sP1;
        const unsigned short* i2 = (j & 1) ? sQ2 : sP2;
        unsigned short* o1 = (j & 1) ? sP1 : sQ1;
        unsigned short* o2 = (j & 1) ? sP2 : sQ2;
        k_gemm_s<4><<<dim3(Hn / 128, M2n / 64), 256, 0, stream>>>(
            i1, i2, a1, a2, Out, o1, o2, nullptr, perm, counts, j);
    }
}

// Round 5
// 1519.051 us; speedup vs baseline: 1.3273x; 1.3273x over previous
//
#include <hip/hip_runtime.h>

#define Hn 2048
#define Bn 8
#define Tn 2048
#define Cn 16
#define NCn (Tn / Cn)     // 128 chunks
#define M2n (NCn * Bn)    // 1024 scan rows

using f32x4 = __attribute__((ext_vector_type(4))) float;
using u32x4 = __attribute__((ext_vector_type(4))) unsigned int;
using us4   = __attribute__((ext_vector_type(4))) unsigned short;
using bf8   = __attribute__((ext_vector_type(8))) short;
using f4    = __attribute__((ext_vector_type(4))) float;

#define GLOAD16(g, l) __builtin_amdgcn_global_load_lds(                      \
    (const __attribute__((address_space(1))) void*)(g),                      \
    (__attribute__((address_space(3))) void*)(l), 16, 0, 0)

__device__ __forceinline__ unsigned short f2bf(float f) {
    unsigned u = __builtin_bit_cast(unsigned, f);
    u = u + 0x7fffu + ((u >> 16) & 1u);
    return (unsigned short)(u >> 16);
}
__device__ __forceinline__ float bf2f(unsigned short h) {
    unsigned u = ((unsigned)h) << 16;
    return __builtin_bit_cast(float, u);
}
__device__ __forceinline__ void split2f(float v, unsigned short& a, unsigned short& b) {
    a = f2bf(v);
    b = f2bf(v - bf2f(a));
}

// ---------------------------------------------------------------------------
// K0: canonicalize reset, firstReset/cut/anyUncut, counting-sort rows by
//     firstReset DESC -> perm/iperm/counts.
// ---------------------------------------------------------------------------
__global__ __launch_bounds__(256) void k_reset_prep(const unsigned int* __restrict__ rin,
                                                    unsigned char* __restrict__ r8,
                                                    int* __restrict__ cut,
                                                    int* __restrict__ firstReset,
                                                    int* __restrict__ anyUncut,
                                                    int* __restrict__ perm,
                                                    int* __restrict__ iperm,
                                                    int* __restrict__ counts) {
    __shared__ int s_badInt, s_badFloat;
    __shared__ int hist[17], off[18], cur[17];
    if (threadIdx.x == 0) { s_badInt = 0; s_badFloat = 0; *anyUncut = 0; }
    if (threadIdx.x < 17) hist[threadIdx.x] = 0;
    __syncthreads();
    int badI = 0, badF = 0;
    for (int i = threadIdx.x; i < 4096; i += 256) {
        unsigned int v = rin[i];
        if (v > 1u) badI = 1;
        if (v != 0u && v != 0x3f800000u) badF = 1;
    }
    if (badI) atomicOr(&s_badInt, 1);
    if (badF) atomicOr(&s_badFloat, 1);
    __syncthreads();
    const int fmt = (!s_badInt) ? 0 : ((!s_badFloat) ? 1 : 2);
    const unsigned char* rb = (const unsigned char*)rin;
    const float* rf = (const float*)rin;
    for (int i = threadIdx.x; i < Bn * Tn; i += 256) {
        unsigned char v;
        if (fmt == 0)      v = (unsigned char)(rin[i] != 0u);
        else if (fmt == 1) v = (unsigned char)(rf[i] != 0.0f);
        else               v = (unsigned char)(rb[i] != 0);
        r8[i] = v;
    }
    __syncthreads();
    int anyU = 0;
    for (int m = threadIdx.x; m < M2n; m += 256) {
        int c = m / Bn, b = m % Bn;
        int fr = Cn;
        for (int j = 0; j < Cn; j++) {
            if (r8[b * Tn + c * Cn + j]) { fr = j; break; }
        }
        firstReset[m] = fr;
        int ct = (fr < Cn);
        cut[m] = ct;
        if (!ct && c < NCn - 1) anyU = 1;
        atomicAdd(&hist[fr], 1);
    }
    if (anyU) atomicOr(anyUncut, 1);
    __syncthreads();
    if (threadIdx.x == 0) {
        off[16] = 0;
        for (int v = 15; v >= 0; v--) off[v] = off[v + 1] + hist[v + 1];
        for (int v = 0; v < 17; v++) cur[v] = (v == 16) ? 0 : off[v];
        for (int j = 0; j < 16; j++) counts[j] = off[j];
    }
    __syncthreads();
    for (int m = threadIdx.x; m < M2n; m += 256) {
        int fr = firstReset[m];
        int pos = atomicAdd(&cur[fr], 1);
        perm[pos] = m;
        iperm[m] = pos;
    }
}

// ---------------------------------------------------------------------------
// Split pre-passes (2-way hi/lo)
// ---------------------------------------------------------------------------
__global__ __launch_bounds__(256) void k_split_A2(const float* __restrict__ A,
                                                  unsigned short* __restrict__ a1,
                                                  unsigned short* __restrict__ a2) {
    size_t i = ((size_t)blockIdx.x * 256 + threadIdx.x) * 4;
    f32x4 v = *(const f32x4*)&A[i];
    us4 h1, h2;
#pragma unroll
    for (int e = 0; e < 4; e++) {
        unsigned short x1, x2;
        split2f(v[e], x1, x2);
        h1[e] = x1; h2[e] = x2;
    }
    *(us4*)&a1[i] = h1; *(us4*)&a2[i] = h2;
}

__global__ __launch_bounds__(256) void k_split_Bt(const float* __restrict__ Bm,
                                                  unsigned short* __restrict__ b1,
                                                  unsigned short* __restrict__ b2) {
    __shared__ float tile[64][65];
    const int k0 = blockIdx.y * 64, n0 = blockIdx.x * 64;
    const int c = threadIdx.x & 63, r4 = threadIdx.x >> 6;
#pragma unroll
    for (int i = 0; i < 16; i++) {
        int r = r4 * 16 + i;
        tile[r][c] = Bm[(size_t)(k0 + r) * Hn + n0 + c];
    }
    __syncthreads();
#pragma unroll
    for (int i = 0; i < 16; i++) {
        int r = r4 * 16 + i;
        float v = tile[c][r];                 // Bm[k0+c][n0+r]
        unsigned short x1, x2;
        split2f(v, x1, x2);
        b1[(size_t)(n0 + r) * Hn + k0 + c] = x1;
        b2[(size_t)(n0 + r) * Hn + k0 + c] = x2;
    }
}

__global__ __launch_bounds__(256) void k_split_X(const float* __restrict__ X,
                                                 unsigned short* __restrict__ x1,
                                                 unsigned short* __restrict__ x2) {
    size_t i = ((size_t)blockIdx.x * 256 + threadIdx.x) * 4;
    f32x4 v = *(const f32x4*)&X[i];
    us4 h1, h2;
#pragma unroll
    for (int e = 0; e < 4; e++) {
        unsigned short a, b;
        split2f(v[e], a, b);
        h1[e] = a; h2[e] = b;
    }
    *(us4*)&x1[i] = h1; *(us4*)&x2[i] = h2;
}

// ---------------------------------------------------------------------------
// Phase-1 GEMM: Out[m,n] = sum_k X[m,k]*Bt[n,k], 3 products.
// 256x128 tile, 512 threads (8 waves, 4m x 2n), FM=FN=4, BK=32, LW=32 linear,
// staging via global_load_lds dwordx4. Fused step0: rows with t%16==0 also
// write chunk-scan initial state splits.
// ---------------------------------------------------------------------------
template<int PREX>
__global__ __launch_bounds__(512) void k_gemm_p1(const unsigned short* __restrict__ X0,
                                                 const unsigned short* __restrict__ X1,
                                                 const unsigned short* __restrict__ B0,
                                                 const unsigned short* __restrict__ B1,
                                                 const float* __restrict__ Xf,
                                                 float* __restrict__ Out,
                                                 unsigned short* __restrict__ S0,
                                                 unsigned short* __restrict__ S1) {
    constexpr int BM = 256, BN = 128, LW = 32;
    __shared__ unsigned short ldsA[2 * BM * LW];   // 32 KB
    __shared__ unsigned short ldsB[2 * BN * LW];   // 16 KB
    const int tid = threadIdx.x;
    const int lane = tid & 63;
    const int wv = tid >> 6;
    const int wm = wv >> 1, wn = wv & 1;
    const int n0 = blockIdx.x * BN;
    const int m0 = blockIdx.y * BM;

    f4 acc[4][4];
#pragma unroll
    for (int fm = 0; fm < 4; fm++)
#pragma unroll
        for (int fn = 0; fn < 4; fn++) acc[fm][fn] = (f4){0.f, 0.f, 0.f, 0.f};

    const unsigned short* gA[4];
    unsigned short* lA[4];
    const float* gX[2];
    unsigned short* lX[2];
    const unsigned short* gB[2];
    unsigned short* lB[2];
    if constexpr (PREX) {
#pragma unroll
        for (int q = 0; q < 4; q++) {
            int u = tid + q * 512;                 // 2048 granules (16B each)
            int sp = u >> 10, row = (u >> 2) & 255, slot = u & 3;
            gA[q] = (sp ? X1 : X0) + (size_t)(m0 + row) * Hn + slot * 8;
            lA[q] = &ldsA[u * 8];                  // linear: lane-order contiguous
        }
    } else {
#pragma unroll
        for (int q = 0; q < 2; q++) {
            int u = tid + q * 512;                 // 1024 items (row x 8 floats)
            int row = u >> 2, slot = u & 3;
            gX[q] = Xf + (size_t)(m0 + row) * Hn + slot * 8;
            lX[q] = &ldsA[row * LW + slot * 8];    // hi plane; lo at +BM*LW
        }
    }
#pragma unroll
    for (int q = 0; q < 2; q++) {
        int u = tid + q * 512;                     // 1024 granules
        int sp = u >> 9, row = (u >> 2) & 127, slot = u & 3;
        gB[q] = (sp ? B1 : B0) + (size_t)(n0 + row) * Hn + slot * 8;
        lB[q] = &ldsB[u * 8];
    }

    for (int k0 = 0; k0 < Hn; k0 += 32) {
        if constexpr (PREX) {
#pragma unroll
            for (int q = 0; q < 4; q++) {
                GLOAD16(gA[q], lA[q]);
                gA[q] += 32;
            }
        } else {
#pragma unroll
            for (int q = 0; q < 2; q++) {
                f32x4 va = *(const f32x4*)gX[q];
                f32x4 vb = *(const f32x4*)(gX[q] + 4);
                gX[q] += 32;
                us4 h1a, h2a, h1b, h2b;
#pragma unroll
                for (int e = 0; e < 4; e++) {
                    unsigned short p, r;
                    split2f(va[e], p, r); h1a[e] = p; h2a[e] = r;
                    split2f(vb[e], p, r); h1b[e] = p; h2b[e] = r;
                }
                *(us4*)lX[q] = h1a;
                *(us4*)(lX[q] + 4) = h1b;
                *(us4*)(lX[q] + BM * LW) = h2a;
                *(us4*)(lX[q] + BM * LW + 4) = h2b;
            }
        }
#pragma unroll
        for (int q = 0; q < 2; q++) {
            GLOAD16(gB[q], lB[q]);
            gB[q] += 32;
        }
        __syncthreads();   // drains vmcnt(0): DMA staging complete

        bf8 af[2][4], bfr[2][4];
#pragma unroll
        for (int sp = 0; sp < 2; sp++)
#pragma unroll
            for (int f = 0; f < 4; f++)
                af[sp][f] = *(const bf8*)&ldsA[(sp * BM + wm * 64 + f * 16 + (lane & 15)) * LW + (lane >> 4) * 8];
#pragma unroll
        for (int sp = 0; sp < 2; sp++)
#pragma unroll
            for (int f = 0; f < 4; f++)
                bfr[sp][f] = *(const bf8*)&ldsB[(sp * BN + wn * 64 + f * 16 + (lane & 15)) * LW + (lane >> 4) * 8];

        const int pa[3] = {0, 0, 1};
        const int pb[3] = {0, 1, 0};
#pragma unroll
        for (int p = 0; p < 3; p++)
#pragma unroll
            for (int fm = 0; fm < 4; fm++)
#pragma unroll
                for (int fn = 0; fn < 4; fn++)
                    acc[fm][fn] = __builtin_amdgcn_mfma_f32_16x16x32_bf16(
                        af[pa[p]][fm], bfr[pb[p]][fn], acc[fm][fn], 0, 0, 0);
        __syncthreads();   // protect LDS reuse before next stage
    }

    // D mapping: row=(lane>>4)*4+r, col=lane&15. Fused step0 for t%16==0 rows.
#pragma unroll
    for (int fm = 0; fm < 4; fm++)
#pragma unroll
        for (int r = 0; r < 4; r++) {
            int row = m0 + wm * 64 + fm * 16 + (lane >> 4) * 4 + r;
            int bb = row >> 11, t = row & 2047;
            int isC0 = ((t & 15) == 0);
            size_t ob = (size_t)row * Hn;
            size_t sb = (size_t)((t >> 4) * 8 + bb) * Hn;
#pragma unroll
            for (int fn = 0; fn < 4; fn++) {
                int n = n0 + wn * 64 + fn * 16 + (lane & 15);
                float v = acc[fm][fn][r];
                Out[ob + n] = v;
                if (isC0) {
                    unsigned short h1, h2;
                    split2f(v, h1, h2);
                    S0[sb + n] = h1; S1[sb + n] = h2;
                }
            }
        }
}

// ---------------------------------------------------------------------------
// Scan / correction GEMM: 64x64 tile, 256 threads (2x2 waves), FM=FN=2,
// LW=32 linear, global_load_lds staging.
// PHASE 2: v=(reset?0:acc)+Out; Out=v; split2 -> state.
// PHASE 3: as PHASE 2 (j=15) + carry: u-splits at iperm[m+8], fp32 Hin[m+8].
// PHASE 4: correction on sorted alive prefix.
// ---------------------------------------------------------------------------
template<int PHASE>
__global__ __launch_bounds__(256) void k_gemm_s(const unsigned short* __restrict__ S0,
                                                const unsigned short* __restrict__ S1,
                                                const unsigned short* __restrict__ W0,
                                                const unsigned short* __restrict__ W1,
                                                float* __restrict__ Out,
                                                unsigned short* __restrict__ O0,
                                                unsigned short* __restrict__ O1,
                                                const unsigned char* __restrict__ r8v,
                                                const int* __restrict__ perm,
                                                const int* __restrict__ iperm,
                                                const int* __restrict__ counts,
                                                unsigned short* __restrict__ U0,
                                                unsigned short* __restrict__ U1,
                                                float* __restrict__ Hin,
                                                int j) {
    constexpr int BM = 64, BN = 64, LW = 32;
    __shared__ unsigned short ldsA[2 * BM * LW];   // 8 KB
    __shared__ unsigned short ldsB[2 * BN * LW];   // 8 KB
    const int tid = threadIdx.x;
    const int lane = tid & 63;
    const int wv = tid >> 6;
    const int wm = wv >> 1, wn = wv & 1;
    const int n0 = blockIdx.x * BN;
    const int m0 = blockIdx.y * BM;

    int cnt = 0;
    if constexpr (PHASE == 4) {
        cnt = counts[j];
        if (m0 >= cnt) return;
    }

    f4 acc[2][2];
#pragma unroll
    for (int fm = 0; fm < 2; fm++)
#pragma unroll
        for (int fn = 0; fn < 2; fn++) acc[fm][fn] = (f4){0.f, 0.f, 0.f, 0.f};

    const unsigned short* gA[2];
    unsigned short* lA[2];
    const unsigned short* gB[2];
    unsigned short* lB[2];
#pragma unroll
    for (int q = 0; q < 2; q++) {
        int u = tid + q * 256;                     // 512 granules
        int sp = u >> 8, row = (u >> 2) & 63, slot = u & 3;
        gA[q] = (sp ? S1 : S0) + (size_t)(m0 + row) * Hn + slot * 8;
        lA[q] = &ldsA[u * 8];
        gB[q] = (sp ? W1 : W0) + (size_t)(n0 + row) * Hn + slot * 8;
        lB[q] = &ldsB[u * 8];
    }

    for (int k0 = 0; k0 < Hn; k0 += 32) {
#pragma unroll
        for (int q = 0; q < 2; q++) {
            GLOAD16(gA[q], lA[q]);
            GLOAD16(gB[q], lB[q]);
            gA[q] += 32;
            gB[q] += 32;
        }
        __syncthreads();

        bf8 af[2][2], bfr[2][2];
#pragma unroll
        for (int sp = 0; sp < 2; sp++)
#pragma unroll
            for (int f = 0; f < 2; f++) {
                af[sp][f] = *(const bf8*)&ldsA[(sp * BM + wm * 32 + f * 16 + (lane & 15)) * LW + (lane >> 4) * 8];
                bfr[sp][f] = *(const bf8*)&ldsB[(sp * BN + wn * 32 + f * 16 + (lane & 15)) * LW + (lane >> 4) * 8];
            }

        const int pa[3] = {0, 0, 1};
        const int pb[3] = {0, 1, 0};
#pragma unroll
        for (int p = 0; p < 3; p++)
#pragma unroll
            for (int fm = 0; fm < 2; fm++)
#pragma unroll
                for (int fn = 0; fn < 2; fn++)
                    acc[fm][fn] = __builtin_amdgcn_mfma_f32_16x16x32_bf16(
                        af[pa[p]][fm], bfr[pb[p]][fn], acc[fm][fn], 0, 0, 0);
        __syncthreads();
    }

    if constexpr (PHASE == 2 || PHASE == 3) {
#pragma unroll
        for (int fm = 0; fm < 2; fm++)
#pragma unroll
            for (int r = 0; r < 4; r++) {
                int m = m0 + wm * 32 + fm * 16 + (lane >> 4) * 4 + r;
                int cch = m >> 3, bb = m & 7;
                int t = cch * Cn + j;
                int rfl = r8v[bb * Tn + t];
                size_t ob = ((size_t)bb * Tn + t) * (size_t)Hn;
                size_t sb = (size_t)m * Hn;
                int carry = 0;
                size_t ub = 0, hb = 0;
                if constexpr (PHASE == 3) {
                    carry = (m < M2n - 8);
                    if (carry) {
                        ub = (size_t)iperm[m + 8] * Hn;
                        hb = (size_t)(m + 8) * Hn;
                    }
                }
#pragma unroll
                for (int fn = 0; fn < 2; fn++) {
                    int n = n0 + wn * 32 + fn * 16 + (lane & 15);
                    float v = (rfl ? 0.0f : acc[fm][fn][r]) + Out[ob + n];
                    Out[ob + n] = v;
                    unsigned short h1, h2;
                    split2f(v, h1, h2);
                    O0[sb + n] = h1; O1[sb + n] = h2;
                    if constexpr (PHASE == 3) {
                        if (carry) {
                            U0[ub + n] = h1; U1[ub + n] = h2;
                            Hin[hb + n] = v;
                        }
                    }
                }
            }
    } else {  // PHASE 4 (sorted prefix)
#pragma unroll
        for (int fm = 0; fm < 2; fm++)
#pragma unroll
            for (int r = 0; r < 4; r++) {
                int s = m0 + wm * 32 + fm * 16 + (lane >> 4) * 4 + r;
                int alive = (s < cnt);
                int m = perm[s];
                int cch = m >> 3, bb = m & 7;
                int t = cch * Cn + j;
                size_t ob = ((size_t)bb * Tn + t) * (size_t)Hn;
                size_t sb = (size_t)s * Hn;
#pragma unroll
                for (int fn = 0; fn < 2; fn++) {
                    int n = n0 + wn * 32 + fn * 16 + (lane & 15);
                    if (alive) {
                        float val = acc[fm][fn][r];
                        unsigned short h1, h2;
                        split2f(val, h1, h2);
                        O0[sb + n] = h1; O1[sb + n] = h2;
                        Out[ob + n] += val;
                    }
                }
            }
    }
}

// ---------------------------------------------------------------------------
// Zero carry state for chunk-0 rows (sorted positions iperm[0..7]) + Hin rows.
// ---------------------------------------------------------------------------
__global__ __launch_bounds__(256) void k_zero_c0(const int* __restrict__ iperm,
                                                 unsigned short* __restrict__ U0,
                                                 unsigned short* __restrict__ U1,
                                                 float* __restrict__ Hin) {
    int b = blockIdx.x;
    int s = iperm[b];
    for (int n = threadIdx.x; n < Hn; n += 256) {
        U0[(size_t)s * Hn + n] = 0;
        U1[(size_t)s * Hn + n] = 0;
        Hin[(size_t)b * Hn + n] = 0.0f;
    }
}

// ---------------------------------------------------------------------------
// Exact fallback for uncut chunks (E[occurrences] ~ 0.016).
// ---------------------------------------------------------------------------
__global__ __launch_bounds__(1024) void k_fallback(float* __restrict__ Hin,
                                                   const float* __restrict__ A,
                                                   const int* __restrict__ cut,
                                                   const int* __restrict__ anyUncut,
                                                   unsigned short* __restrict__ u1,
                                                   unsigned short* __restrict__ u2,
                                                   const int* __restrict__ iperm) {
    if (*anyUncut == 0) return;
    __shared__ float v0[Hn];
    __shared__ float v1[Hn];
    for (int c = 1; c < NCn; c++) {
        for (int b = 0; b < Bn; b++) {
            if (cut[(c - 1) * Bn + b]) continue;
            for (int n = threadIdx.x; n < Hn; n += 1024)
                v0[n] = Hin[((size_t)(c - 1) * Bn + b) * Hn + n];
            __syncthreads();
            for (int s = 0; s < Cn; s++) {
                float* pin = (s & 1) ? v1 : v0;
                float* pout = (s & 1) ? v0 : v1;
                for (int n = threadIdx.x; n < Hn; n += 1024) {
                    float accv = 0.0f;
                    const float* Ar = &A[(size_t)n * Hn];
                    for (int k = 0; k < Hn; k++) accv += pin[k] * Ar[k];
                    pout[n] = accv;
                }
                __syncthreads();
            }
            float* pres = (Cn & 1) ? v1 : v0;
            int mrow = c * Bn + b;
            size_t dst = (size_t)mrow * Hn;
            size_t sdst = (size_t)iperm[mrow] * Hn;
            for (int n = threadIdx.x; n < Hn; n += 1024) {
                float nv = Hin[dst + n] + pres[n];
                Hin[dst + n] = nv;
                unsigned short h1, h2;
                split2f(nv, h1, h2);
                u1[sdst + n] = h1; u2[sdst + n] = h2;
            }
            __syncthreads();
        }
    }
}

extern "C" void kernel_launch(void* const* d_in, const int* in_sizes, int n_in,
                              void* d_out, int out_size, void* d_ws, size_t ws_size,
                              hipStream_t stream) {
    const float* x = (const float*)d_in[0];
    const unsigned int* rst = (const unsigned int*)d_in[1];
    const float* Am = (const float*)d_in[2];
    const float* Bm = (const float*)d_in[3];
    float* Out = (float*)d_out;
    char* ws = (char*)d_ws;

    unsigned char* r8 = (unsigned char*)ws;                 // 16 KB
    int* cut = (int*)(ws + 16384);
    int* firstReset = (int*)(ws + 20480);
    int* perm = (int*)(ws + 24576);
    int* iperm = (int*)(ws + 28672);
    int* counts = (int*)(ws + 32768);
    int* anyUncut = (int*)(ws + 32832);
    unsigned short* a1 = (unsigned short*)(ws + 65536);     // A splits [n][k], 8MB ea
    unsigned short* a2 = a1 + 4194304;
    unsigned short* b1 = a2 + 4194304;                      // Bt splits [n][k], 8MB ea
    unsigned short* b2 = b1 + 4194304;
    unsigned short* sP1 = b2 + 4194304;                     // state splits, 4MB ea
    unsigned short* sP2 = sP1 + 2097152;
    unsigned short* sQ1 = sP2 + 2097152;
    unsigned short* sQ2 = sQ1 + 2097152;
    unsigned short* uP1 = sQ2 + 2097152;                    // carry u splits, 4MB ea
    unsigned short* uP2 = uP1 + 2097152;
    float* Hin = (float*)(uP2 + 2097152);                   // 8MB fp32
    unsigned short* x1 = (unsigned short*)(Hin + 2097152);  // X splits, 67MB ea
    unsigned short* x2 = x1 + 33554432;
    const size_t NEED_X = 201392128ull;
    const bool prex = (ws_size >= NEED_X);

    k_reset_prep<<<1, 256, 0, stream>>>(rst, r8, cut, firstReset, anyUncut, perm, iperm, counts);
    k_split_A2<<<4096, 256, 0, stream>>>(Am, a1, a2);
    k_split_Bt<<<dim3(32, 32), 256, 0, stream>>>(Bm, b1, b2);

    // Phase 1: bx = x @ B  (fused step0 -> sP)
    if (prex) {
        k_split_X<<<32768, 256, 0, stream>>>(x, x1, x2);
        k_gemm_p1<1><<<dim3(Hn / 128, (Bn * Tn) / 256), 512, 0, stream>>>(
            x1, x2, b1, b2, nullptr, Out, sP1, sP2);
    } else {
        k_gemm_p1<0><<<dim3(Hn / 128, (Bn * Tn) / 256), 512, 0, stream>>>(
            nullptr, nullptr, b1, b2, x, Out, sP1, sP2);
    }

    // Phase 2: chunk-local scans (j=15 carries h_in into uP/Hin)
    for (int j = 1; j < Cn; j++) {
        const unsigned short* i1 = (j & 1) ? sP1 : sQ1;
        const unsigned short* i2 = (j & 1) ? sP2 : sQ2;
        unsigned short* o1 = (j & 1) ? sQ1 : sP1;
        unsigned short* o2 = (j & 1) ? sQ2 : sP2;
        if (j < Cn - 1) {
            k_gemm_s<2><<<dim3(Hn / 64, M2n / 64), 256, 0, stream>>>(
                i1, i2, a1, a2, Out, o1, o2, r8, nullptr, nullptr, nullptr,
                nullptr, nullptr, nullptr, j);
        } else {
            k_gemm_s<3><<<dim3(Hn / 64, M2n / 64), 256, 0, stream>>>(
                i1, i2, a1, a2, Out, o1, o2, r8, nullptr, iperm, nullptr,
                uP1, uP2, Hin, j);
        }
    }

    // Phase 3: chunk-0 carry zero + exact fallback for uncut chunks
    k_zero_c0<<<8, 256, 0, stream>>>(iperm, uP1, uP2, Hin);
    k_fallback<<<1, 1024, 0, stream>>>(Hin, Am, cut, anyUncut, uP1, uP2, iperm);

    // Phase 4: corrections on shrinking sorted prefix
    for (int j = 0; j < Cn; j++) {
        const unsigned short* i1 = (j == 0) ? uP1 : ((j & 1) ? sP1 : sQ1);
        const unsigned short* i2 = (j == 0) ? uP2 : ((j & 1) ? sP2 : sQ2);
        unsigned short* o1 = (j & 1) ? sQ1 : sP1;
        unsigned short* o2 = (j & 1) ? sQ2 : sP2;
        k_gemm_s<4><<<dim3(Hn / 64, M2n / 64), 256, 0, stream>>>(
            i1, i2, a1, a2, Out, o1, o2, nullptr, perm, nullptr, counts,
            nullptr, nullptr, nullptr, j);
    }
}

// Round 6
// 1348.936 us; speedup vs baseline: 1.4946x; 1.1261x over previous
//
#include <hip/hip_runtime.h>

#define Hn 2048
#define Bn 8
#define Tn 2048
#define Cn 16
#define NCn (Tn / Cn)     // 128 chunks
#define M2n (NCn * Bn)    // 1024 scan rows

using f32x4 = __attribute__((ext_vector_type(4))) float;
using u32x4 = __attribute__((ext_vector_type(4))) unsigned int;
using us4   = __attribute__((ext_vector_type(4))) unsigned short;
using bf8   = __attribute__((ext_vector_type(8))) short;
using f4    = __attribute__((ext_vector_type(4))) float;

#define GLOAD16(g, l) __builtin_amdgcn_global_load_lds(                      \
    (const __attribute__((address_space(1))) void*)(g),                      \
    (__attribute__((address_space(3))) void*)(l), 16, 0, 0)

__device__ __forceinline__ unsigned short f2bf(float f) {
    unsigned u = __builtin_bit_cast(unsigned, f);
    u = u + 0x7fffu + ((u >> 16) & 1u);
    return (unsigned short)(u >> 16);
}
__device__ __forceinline__ float bf2f(unsigned short h) {
    unsigned u = ((unsigned)h) << 16;
    return __builtin_bit_cast(float, u);
}
__device__ __forceinline__ void split2f(float v, unsigned short& a, unsigned short& b) {
    a = f2bf(v);
    b = f2bf(v - bf2f(a));
}

// ---------------------------------------------------------------------------
// K0: canonicalize reset, firstReset/cut/anyUncut, counting-sort rows by
//     firstReset DESC -> perm/iperm/counts.
// ---------------------------------------------------------------------------
__global__ __launch_bounds__(256) void k_reset_prep(const unsigned int* __restrict__ rin,
                                                    unsigned char* __restrict__ r8,
                                                    int* __restrict__ cut,
                                                    int* __restrict__ firstReset,
                                                    int* __restrict__ anyUncut,
                                                    int* __restrict__ perm,
                                                    int* __restrict__ iperm,
                                                    int* __restrict__ counts) {
    __shared__ int s_badInt, s_badFloat;
    __shared__ int hist[17], off[18], cur[17];
    if (threadIdx.x == 0) { s_badInt = 0; s_badFloat = 0; *anyUncut = 0; }
    if (threadIdx.x < 17) hist[threadIdx.x] = 0;
    __syncthreads();
    int badI = 0, badF = 0;
    for (int i = threadIdx.x; i < 4096; i += 256) {
        unsigned int v = rin[i];
        if (v > 1u) badI = 1;
        if (v != 0u && v != 0x3f800000u) badF = 1;
    }
    if (badI) atomicOr(&s_badInt, 1);
    if (badF) atomicOr(&s_badFloat, 1);
    __syncthreads();
    const int fmt = (!s_badInt) ? 0 : ((!s_badFloat) ? 1 : 2);
    const unsigned char* rb = (const unsigned char*)rin;
    const float* rf = (const float*)rin;
    for (int i = threadIdx.x; i < Bn * Tn; i += 256) {
        unsigned char v;
        if (fmt == 0)      v = (unsigned char)(rin[i] != 0u);
        else if (fmt == 1) v = (unsigned char)(rf[i] != 0.0f);
        else               v = (unsigned char)(rb[i] != 0);
        r8[i] = v;
    }
    __syncthreads();
    int anyU = 0;
    for (int m = threadIdx.x; m < M2n; m += 256) {
        int c = m / Bn, b = m % Bn;
        int fr = Cn;
        for (int j = 0; j < Cn; j++) {
            if (r8[b * Tn + c * Cn + j]) { fr = j; break; }
        }
        firstReset[m] = fr;
        int ct = (fr < Cn);
        cut[m] = ct;
        if (!ct && c < NCn - 1) anyU = 1;
        atomicAdd(&hist[fr], 1);
    }
    if (anyU) atomicOr(anyUncut, 1);
    __syncthreads();
    if (threadIdx.x == 0) {
        off[16] = 0;
        for (int v = 15; v >= 0; v--) off[v] = off[v + 1] + hist[v + 1];
        for (int v = 0; v < 17; v++) cur[v] = (v == 16) ? 0 : off[v];
        for (int j = 0; j < 16; j++) counts[j] = off[j];
    }
    __syncthreads();
    for (int m = threadIdx.x; m < M2n; m += 256) {
        int fr = firstReset[m];
        int pos = atomicAdd(&cur[fr], 1);
        perm[pos] = m;
        iperm[m] = pos;
    }
}

// ---------------------------------------------------------------------------
// Split pre-passes (2-way hi/lo)
// ---------------------------------------------------------------------------
__global__ __launch_bounds__(256) void k_split_A2(const float* __restrict__ A,
                                                  unsigned short* __restrict__ a1,
                                                  unsigned short* __restrict__ a2) {
    size_t i = ((size_t)blockIdx.x * 256 + threadIdx.x) * 4;
    f32x4 v = *(const f32x4*)&A[i];
    us4 h1, h2;
#pragma unroll
    for (int e = 0; e < 4; e++) {
        unsigned short x1, x2;
        split2f(v[e], x1, x2);
        h1[e] = x1; h2[e] = x2;
    }
    *(us4*)&a1[i] = h1; *(us4*)&a2[i] = h2;
}

__global__ __launch_bounds__(256) void k_split_Bt(const float* __restrict__ Bm,
                                                  unsigned short* __restrict__ b1,
                                                  unsigned short* __restrict__ b2) {
    __shared__ float tile[64][65];
    const int k0 = blockIdx.y * 64, n0 = blockIdx.x * 64;
    const int c = threadIdx.x & 63, r4 = threadIdx.x >> 6;
#pragma unroll
    for (int i = 0; i < 16; i++) {
        int r = r4 * 16 + i;
        tile[r][c] = Bm[(size_t)(k0 + r) * Hn + n0 + c];
    }
    __syncthreads();
#pragma unroll
    for (int i = 0; i < 16; i++) {
        int r = r4 * 16 + i;
        float v = tile[c][r];                 // Bm[k0+c][n0+r]
        unsigned short x1, x2;
        split2f(v, x1, x2);
        b1[(size_t)(n0 + r) * Hn + k0 + c] = x1;
        b2[(size_t)(n0 + r) * Hn + k0 + c] = x2;
    }
}

__global__ __launch_bounds__(256) void k_split_X(const float* __restrict__ X,
                                                 unsigned short* __restrict__ x1,
                                                 unsigned short* __restrict__ x2) {
    size_t i = ((size_t)blockIdx.x * 256 + threadIdx.x) * 4;
    f32x4 v = *(const f32x4*)&X[i];
    us4 h1, h2;
#pragma unroll
    for (int e = 0; e < 4; e++) {
        unsigned short a, b;
        split2f(v[e], a, b);
        h1[e] = a; h2[e] = b;
    }
    *(us4*)&x1[i] = h1; *(us4*)&x2[i] = h2;
}

// ---------------------------------------------------------------------------
// Phase-1 GEMM: Out[m,n] = sum_k X[m,k]*Bt[n,k], 3 products.
// 256x128 tile, 512 threads (8 waves, 4m x 2n), FM=FN=4, BK=32.
// Granule swizzle: LDS slot s holds global granule g = s ^ ((row>>1)&3)
// -> ds_read_b128 fragment loads are bank-conflict-free (256 distinct words).
// Fused step0: rows with t%16==0 also write chunk-scan initial state splits.
// ---------------------------------------------------------------------------
template<int PREX>
__global__ __launch_bounds__(512) void k_gemm_p1(const unsigned short* __restrict__ X0,
                                                 const unsigned short* __restrict__ X1,
                                                 const unsigned short* __restrict__ B0,
                                                 const unsigned short* __restrict__ B1,
                                                 const float* __restrict__ Xf,
                                                 float* __restrict__ Out,
                                                 unsigned short* __restrict__ S0,
                                                 unsigned short* __restrict__ S1) {
    constexpr int BM = 256, BN = 128, LW = 32;
    __shared__ unsigned short ldsA[2 * BM * LW];   // 32 KB
    __shared__ unsigned short ldsB[2 * BN * LW];   // 16 KB
    const int tid = threadIdx.x;
    const int lane = tid & 63;
    const int wv = tid >> 6;
    const int wm = wv >> 1, wn = wv & 1;
    const int n0 = blockIdx.x * BN;
    const int m0 = blockIdx.y * BM;

    f4 acc[4][4];
#pragma unroll
    for (int fm = 0; fm < 4; fm++)
#pragma unroll
        for (int fn = 0; fn < 4; fn++) acc[fm][fn] = (f4){0.f, 0.f, 0.f, 0.f};

    const unsigned short* gA[4];
    unsigned short* lA[4];
    const float* gX[2];
    unsigned short* lX[2];
    const unsigned short* gB[2];
    unsigned short* lB[2];
    if constexpr (PREX) {
#pragma unroll
        for (int q = 0; q < 4; q++) {
            int u = tid + q * 512;                 // 2048 granules (16B each)
            int sp = u >> 10, row = (u >> 2) & 255, slot = u & 3;
            int g = slot ^ ((row >> 1) & 3);       // swizzled source granule
            gA[q] = (sp ? X1 : X0) + (size_t)(m0 + row) * Hn + g * 8;
            lA[q] = &ldsA[u * 8];                  // linear LDS dest
        }
    } else {
#pragma unroll
        for (int q = 0; q < 2; q++) {
            int u = tid + q * 512;                 // 1024 items (row x granule)
            int row = u >> 2, slot = u & 3;
            int s = slot ^ ((row >> 1) & 3);       // swizzled LDS slot
            gX[q] = Xf + (size_t)row * 0 + (size_t)(m0 + row) * Hn + slot * 8;
            lX[q] = &ldsA[row * LW + s * 8];       // hi plane; lo at +BM*LW
        }
    }
#pragma unroll
    for (int q = 0; q < 2; q++) {
        int u = tid + q * 512;                     // 1024 granules
        int sp = u >> 9, row = (u >> 2) & 127, slot = u & 3;
        int g = slot ^ ((row >> 1) & 3);
        gB[q] = (sp ? B1 : B0) + (size_t)(n0 + row) * Hn + g * 8;
        lB[q] = &ldsB[u * 8];
    }
    const int sl = (lane >> 4) ^ ((lane >> 1) & 3);   // read-side slot per lane

    for (int k0 = 0; k0 < Hn; k0 += 32) {
        if constexpr (PREX) {
#pragma unroll
            for (int q = 0; q < 4; q++) {
                GLOAD16(gA[q], lA[q]);
                gA[q] += 32;
            }
        } else {
#pragma unroll
            for (int q = 0; q < 2; q++) {
                f32x4 va = *(const f32x4*)gX[q];
                f32x4 vb = *(const f32x4*)(gX[q] + 4);
                gX[q] += 32;
                us4 h1a, h2a, h1b, h2b;
#pragma unroll
                for (int e = 0; e < 4; e++) {
                    unsigned short p, r;
                    split2f(va[e], p, r); h1a[e] = p; h2a[e] = r;
                    split2f(vb[e], p, r); h1b[e] = p; h2b[e] = r;
                }
                *(us4*)lX[q] = h1a;
                *(us4*)(lX[q] + 4) = h1b;
                *(us4*)(lX[q] + BM * LW) = h2a;
                *(us4*)(lX[q] + BM * LW + 4) = h2b;
            }
        }
#pragma unroll
        for (int q = 0; q < 2; q++) {
            GLOAD16(gB[q], lB[q]);
            gB[q] += 32;
        }
        __syncthreads();   // drains vmcnt(0): DMA staging complete

        bf8 af[2][4], bfr[2][4];
#pragma unroll
        for (int sp = 0; sp < 2; sp++)
#pragma unroll
            for (int f = 0; f < 4; f++)
                af[sp][f] = *(const bf8*)&ldsA[(sp * BM + wm * 64 + f * 16 + (lane & 15)) * LW + sl * 8];
#pragma unroll
        for (int sp = 0; sp < 2; sp++)
#pragma unroll
            for (int f = 0; f < 4; f++)
                bfr[sp][f] = *(const bf8*)&ldsB[(sp * BN + wn * 64 + f * 16 + (lane & 15)) * LW + sl * 8];

        const int pa[3] = {0, 0, 1};
        const int pb[3] = {0, 1, 0};
#pragma unroll
        for (int p = 0; p < 3; p++)
#pragma unroll
            for (int fm = 0; fm < 4; fm++)
#pragma unroll
                for (int fn = 0; fn < 4; fn++)
                    acc[fm][fn] = __builtin_amdgcn_mfma_f32_16x16x32_bf16(
                        af[pa[p]][fm], bfr[pb[p]][fn], acc[fm][fn], 0, 0, 0);
        __syncthreads();   // protect LDS reuse before next stage
    }

    // D mapping: row=(lane>>4)*4+r, col=lane&15. Fused step0 for t%16==0 rows.
#pragma unroll
    for (int fm = 0; fm < 4; fm++)
#pragma unroll
        for (int r = 0; r < 4; r++) {
            int row = m0 + wm * 64 + fm * 16 + (lane >> 4) * 4 + r;
            int bb = row >> 11, t = row & 2047;
            int isC0 = ((t & 15) == 0);
            size_t ob = (size_t)row * Hn;
            size_t sb = (size_t)((t >> 4) * 8 + bb) * Hn;
#pragma unroll
            for (int fn = 0; fn < 4; fn++) {
                int n = n0 + wn * 64 + fn * 16 + (lane & 15);
                float v = acc[fm][fn][r];
                Out[ob + n] = v;
                if (isC0) {
                    unsigned short h1, h2;
                    split2f(v, h1, h2);
                    S0[sb + n] = h1; S1[sb + n] = h2;
                }
            }
        }
}

// ---------------------------------------------------------------------------
// Scan / correction GEMM: 64x64 tile, 256 threads (2x2 waves), FM=FN=2,
// BK=64, granule swizzle s = g ^ (row&7) -> conflict-free ds_read_b128.
// PHASE 2: v=(reset?0:acc)+Out; Out=v; split2 -> state.
// PHASE 3: as PHASE 2 (j=15) + carry: u-splits at iperm[m+8], fp32 Hin[m+8].
// PHASE 4: correction on sorted alive prefix.
// ---------------------------------------------------------------------------
template<int PHASE>
__global__ __launch_bounds__(256) void k_gemm_s(const unsigned short* __restrict__ S0,
                                                const unsigned short* __restrict__ S1,
                                                const unsigned short* __restrict__ W0,
                                                const unsigned short* __restrict__ W1,
                                                float* __restrict__ Out,
                                                unsigned short* __restrict__ O0,
                                                unsigned short* __restrict__ O1,
                                                const unsigned char* __restrict__ r8v,
                                                const int* __restrict__ perm,
                                                const int* __restrict__ iperm,
                                                const int* __restrict__ counts,
                                                unsigned short* __restrict__ U0,
                                                unsigned short* __restrict__ U1,
                                                float* __restrict__ Hin,
                                                int j) {
    constexpr int BM = 64, BN = 64, BK = 64;
    __shared__ unsigned short ldsA[2 * BM * BK];   // 16 KB
    __shared__ unsigned short ldsB[2 * BN * BK];   // 16 KB
    const int tid = threadIdx.x;
    const int lane = tid & 63;
    const int wv = tid >> 6;
    const int wm = wv >> 1, wn = wv & 1;
    const int n0 = blockIdx.x * BN;
    const int m0 = blockIdx.y * BM;

    int cnt = 0;
    if constexpr (PHASE == 4) {
        cnt = counts[j];
        if (m0 >= cnt) return;
    }

    f4 acc[2][2];
#pragma unroll
    for (int fm = 0; fm < 2; fm++)
#pragma unroll
        for (int fn = 0; fn < 2; fn++) acc[fm][fn] = (f4){0.f, 0.f, 0.f, 0.f};

    const unsigned short* gA[4];
    unsigned short* lA[4];
    const unsigned short* gB[4];
    unsigned short* lB[4];
#pragma unroll
    for (int q = 0; q < 4; q++) {
        int u = tid + q * 256;                     // 1024 granules per operand
        int sp = u >> 9, row = (u >> 3) & 63, s = u & 7;
        int g = s ^ (row & 7);                     // swizzled source granule
        gA[q] = (sp ? S1 : S0) + (size_t)(m0 + row) * Hn + g * 8;
        lA[q] = &ldsA[u * 8];
        gB[q] = (sp ? W1 : W0) + (size_t)(n0 + row) * Hn + g * 8;
        lB[q] = &ldsB[u * 8];
    }

    for (int k0 = 0; k0 < Hn; k0 += BK) {
#pragma unroll
        for (int q = 0; q < 4; q++) {
            GLOAD16(gA[q], lA[q]);
            GLOAD16(gB[q], lB[q]);
            gA[q] += BK;
            gB[q] += BK;
        }
        __syncthreads();

        const int pa[3] = {0, 0, 1};
        const int pb[3] = {0, 1, 0};
#pragma unroll
        for (int h = 0; h < 2; h++) {
            const int sl = (h * 4 + (lane >> 4)) ^ (lane & 7);
            bf8 af[2][2], bfr[2][2];
#pragma unroll
            for (int sp = 0; sp < 2; sp++)
#pragma unroll
                for (int f = 0; f < 2; f++) {
                    af[sp][f] = *(const bf8*)&ldsA[(sp * BM + wm * 32 + f * 16 + (lane & 15)) * BK + sl * 8];
                    bfr[sp][f] = *(const bf8*)&ldsB[(sp * BN + wn * 32 + f * 16 + (lane & 15)) * BK + sl * 8];
                }
#pragma unroll
            for (int p = 0; p < 3; p++)
#pragma unroll
                for (int fm = 0; fm < 2; fm++)
#pragma unroll
                    for (int fn = 0; fn < 2; fn++)
                        acc[fm][fn] = __builtin_amdgcn_mfma_f32_16x16x32_bf16(
                            af[pa[p]][fm], bfr[pb[p]][fn], acc[fm][fn], 0, 0, 0);
        }
        __syncthreads();
    }

    if constexpr (PHASE == 2 || PHASE == 3) {
#pragma unroll
        for (int fm = 0; fm < 2; fm++)
#pragma unroll
            for (int r = 0; r < 4; r++) {
                int m = m0 + wm * 32 + fm * 16 + (lane >> 4) * 4 + r;
                int cch = m >> 3, bb = m & 7;
                int t = cch * Cn + j;
                int rfl = r8v[bb * Tn + t];
                size_t ob = ((size_t)bb * Tn + t) * (size_t)Hn;
                size_t sb = (size_t)m * Hn;
                int carry = 0;
                size_t ub = 0, hb = 0;
                if constexpr (PHASE == 3) {
                    carry = (m < M2n - 8);
                    if (carry) {
                        ub = (size_t)iperm[m + 8] * Hn;
                        hb = (size_t)(m + 8) * Hn;
                    }
                }
#pragma unroll
                for (int fn = 0; fn < 2; fn++) {
                    int n = n0 + wn * 32 + fn * 16 + (lane & 15);
                    float v = (rfl ? 0.0f : acc[fm][fn][r]) + Out[ob + n];
                    Out[ob + n] = v;
                    unsigned short h1, h2;
                    split2f(v, h1, h2);
                    O0[sb + n] = h1; O1[sb + n] = h2;
                    if constexpr (PHASE == 3) {
                        if (carry) {
                            U0[ub + n] = h1; U1[ub + n] = h2;
                            Hin[hb + n] = v;
                        }
                    }
                }
            }
    } else {  // PHASE 4 (sorted prefix)
#pragma unroll
        for (int fm = 0; fm < 2; fm++)
#pragma unroll
            for (int r = 0; r < 4; r++) {
                int s = m0 + wm * 32 + fm * 16 + (lane >> 4) * 4 + r;
                int alive = (s < cnt);
                int m = perm[s];
                int cch = m >> 3, bb = m & 7;
                int t = cch * Cn + j;
                size_t ob = ((size_t)bb * Tn + t) * (size_t)Hn;
                size_t sb = (size_t)s * Hn;
#pragma unroll
                for (int fn = 0; fn < 2; fn++) {
                    int n = n0 + wn * 32 + fn * 16 + (lane & 15);
                    if (alive) {
                        float val = acc[fm][fn][r];
                        unsigned short h1, h2;
                        split2f(val, h1, h2);
                        O0[sb + n] = h1; O1[sb + n] = h2;
                        Out[ob + n] += val;
                    }
                }
            }
    }
}

// ---------------------------------------------------------------------------
// Zero carry state for chunk-0 rows (sorted positions iperm[0..7]) + Hin rows.
// ---------------------------------------------------------------------------
__global__ __launch_bounds__(256) void k_zero_c0(const int* __restrict__ iperm,
                                                 unsigned short* __restrict__ U0,
                                                 unsigned short* __restrict__ U1,
                                                 float* __restrict__ Hin) {
    int b = blockIdx.x;
    int s = iperm[b];
    for (int n = threadIdx.x; n < Hn; n += 256) {
        U0[(size_t)s * Hn + n] = 0;
        U1[(size_t)s * Hn + n] = 0;
        Hin[(size_t)b * Hn + n] = 0.0f;
    }
}

// ---------------------------------------------------------------------------
// Exact fallback for uncut chunks (E[occurrences] ~ 0.016).
// ---------------------------------------------------------------------------
__global__ __launch_bounds__(1024) void k_fallback(float* __restrict__ Hin,
                                                   const float* __restrict__ A,
                                                   const int* __restrict__ cut,
                                                   const int* __restrict__ anyUncut,
                                                   unsigned short* __restrict__ u1,
                                                   unsigned short* __restrict__ u2,
                                                   const int* __restrict__ iperm) {
    if (*anyUncut == 0) return;
    __shared__ float v0[Hn];
    __shared__ float v1[Hn];
    for (int c = 1; c < NCn; c++) {
        for (int b = 0; b < Bn; b++) {
            if (cut[(c - 1) * Bn + b]) continue;
            for (int n = threadIdx.x; n < Hn; n += 1024)
                v0[n] = Hin[((size_t)(c - 1) * Bn + b) * Hn + n];
            __syncthreads();
            for (int s = 0; s < Cn; s++) {
                float* pin = (s & 1) ? v1 : v0;
                float* pout = (s & 1) ? v0 : v1;
                for (int n = threadIdx.x; n < Hn; n += 1024) {
                    float accv = 0.0f;
                    const float* Ar = &A[(size_t)n * Hn];
                    for (int k = 0; k < Hn; k++) accv += pin[k] * Ar[k];
                    pout[n] = accv;
                }
                __syncthreads();
            }
            float* pres = (Cn & 1) ? v1 : v0;
            int mrow = c * Bn + b;
            size_t dst = (size_t)mrow * Hn;
            size_t sdst = (size_t)iperm[mrow] * Hn;
            for (int n = threadIdx.x; n < Hn; n += 1024) {
                float nv = Hin[dst + n] + pres[n];
                Hin[dst + n] = nv;
                unsigned short h1, h2;
                split2f(nv, h1, h2);
                u1[sdst + n] = h1; u2[sdst + n] = h2;
            }
            __syncthreads();
        }
    }
}

extern "C" void kernel_launch(void* const* d_in, const int* in_sizes, int n_in,
                              void* d_out, int out_size, void* d_ws, size_t ws_size,
                              hipStream_t stream) {
    const float* x = (const float*)d_in[0];
    const unsigned int* rst = (const unsigned int*)d_in[1];
    const float* Am = (const float*)d_in[2];
    const float* Bm = (const float*)d_in[3];
    float* Out = (float*)d_out;
    char* ws = (char*)d_ws;

    unsigned char* r8 = (unsigned char*)ws;                 // 16 KB
    int* cut = (int*)(ws + 16384);
    int* firstReset = (int*)(ws + 20480);
    int* perm = (int*)(ws + 24576);
    int* iperm = (int*)(ws + 28672);
    int* counts = (int*)(ws + 32768);
    int* anyUncut = (int*)(ws + 32832);
    unsigned short* a1 = (unsigned short*)(ws + 65536);     // A splits [n][k], 8MB ea
    unsigned short* a2 = a1 + 4194304;
    unsigned short* b1 = a2 + 4194304;                      // Bt splits [n][k], 8MB ea
    unsigned short* b2 = b1 + 4194304;
    unsigned short* sP1 = b2 + 4194304;                     // state splits, 4MB ea
    unsigned short* sP2 = sP1 + 2097152;
    unsigned short* sQ1 = sP2 + 2097152;
    unsigned short* sQ2 = sQ1 + 2097152;
    unsigned short* uP1 = sQ2 + 2097152;                    // carry u splits, 4MB ea
    unsigned short* uP2 = uP1 + 2097152;
    float* Hin = (float*)(uP2 + 2097152);                   // 8MB fp32
    unsigned short* x1 = (unsigned short*)(Hin + 2097152);  // X splits, 67MB ea
    unsigned short* x2 = x1 + 33554432;
    const size_t NEED_X = 201392128ull;
    const bool prex = (ws_size >= NEED_X);

    k_reset_prep<<<1, 256, 0, stream>>>(rst, r8, cut, firstReset, anyUncut, perm, iperm, counts);
    k_split_A2<<<4096, 256, 0, stream>>>(Am, a1, a2);
    k_split_Bt<<<dim3(32, 32), 256, 0, stream>>>(Bm, b1, b2);

    // Phase 1: bx = x @ B  (fused step0 -> sP)
    if (prex) {
        k_split_X<<<32768, 256, 0, stream>>>(x, x1, x2);
        k_gemm_p1<1><<<dim3(Hn / 128, (Bn * Tn) / 256), 512, 0, stream>>>(
            x1, x2, b1, b2, nullptr, Out, sP1, sP2);
    } else {
        k_gemm_p1<0><<<dim3(Hn / 128, (Bn * Tn) / 256), 512, 0, stream>>>(
            nullptr, nullptr, b1, b2, x, Out, sP1, sP2);
    }

    // Phase 2: chunk-local scans (j=15 carries h_in into uP/Hin)
    for (int j = 1; j < Cn; j++) {
        const unsigned short* i1 = (j & 1) ? sP1 : sQ1;
        const unsigned short* i2 = (j & 1) ? sP2 : sQ2;
        unsigned short* o1 = (j & 1) ? sQ1 : sP1;
        unsigned short* o2 = (j & 1) ? sQ2 : sP2;
        if (j < Cn - 1) {
            k_gemm_s<2><<<dim3(Hn / 64, M2n / 64), 256, 0, stream>>>(
                i1, i2, a1, a2, Out, o1, o2, r8, nullptr, nullptr, nullptr,
                nullptr, nullptr, nullptr, j);
        } else {
            k_gemm_s<3><<<dim3(Hn / 64, M2n / 64), 256, 0, stream>>>(
                i1, i2, a1, a2, Out, o1, o2, r8, nullptr, iperm, nullptr,
                uP1, uP2, Hin, j);
        }
    }

    // Phase 3: chunk-0 carry zero + exact fallback for uncut chunks
    k_zero_c0<<<8, 256, 0, stream>>>(iperm, uP1, uP2, Hin);
    k_fallback<<<1, 1024, 0, stream>>>(Hin, Am, cut, anyUncut, uP1, uP2, iperm);

    // Phase 4: corrections on shrinking sorted prefix
    for (int j = 0; j < Cn; j++) {
        const unsigned short* i1 = (j == 0) ? uP1 : ((j & 1) ? sP1 : sQ1);
        const unsigned short* i2 = (j == 0) ? uP2 : ((j & 1) ? sP2 : sQ2);
        unsigned short* o1 = (j & 1) ? sQ1 : sP1;
        unsigned short* o2 = (j & 1) ? sQ2 : sP2;
        k_gemm_s<4><<<dim3(Hn / 64, M2n / 64), 256, 0, stream>>>(
            i1, i2, a1, a2, Out, o1, o2, nullptr, perm, nullptr, counts,
            nullptr, nullptr, nullptr, j);
    }
}

// Round 7
// 1287.612 us; speedup vs baseline: 1.5658x; 1.0476x over previous
//
#include <hip/hip_runtime.h>

#define Hn 2048
#define Bn 8
#define Tn 2048
#define Cn 16
#define NCn (Tn / Cn)     // 128 chunks
#define M2n (NCn * Bn)    // 1024 scan rows

using f32x4 = __attribute__((ext_vector_type(4))) float;
using u32x4 = __attribute__((ext_vector_type(4))) unsigned int;
using us4   = __attribute__((ext_vector_type(4))) unsigned short;
using bf8   = __attribute__((ext_vector_type(8))) short;
using f4    = __attribute__((ext_vector_type(4))) float;

#define GLOAD16(g, l) __builtin_amdgcn_global_load_lds(                      \
    (const __attribute__((address_space(1))) void*)(g),                      \
    (__attribute__((address_space(3))) void*)(l), 16, 0, 0)

__device__ __forceinline__ unsigned short f2bf(float f) {
    unsigned u = __builtin_bit_cast(unsigned, f);
    u = u + 0x7fffu + ((u >> 16) & 1u);
    return (unsigned short)(u >> 16);
}
__device__ __forceinline__ float bf2f(unsigned short h) {
    unsigned u = ((unsigned)h) << 16;
    return __builtin_bit_cast(float, u);
}
__device__ __forceinline__ void split2f(float v, unsigned short& a, unsigned short& b) {
    a = f2bf(v);
    b = f2bf(v - bf2f(a));
}

// ---------------------------------------------------------------------------
// K0: canonicalize reset, firstReset/cut/anyUncut, counting-sort rows by
//     firstReset DESC -> perm/iperm/counts.
// ---------------------------------------------------------------------------
__global__ __launch_bounds__(256) void k_reset_prep(const unsigned int* __restrict__ rin,
                                                    unsigned char* __restrict__ r8,
                                                    int* __restrict__ cut,
                                                    int* __restrict__ firstReset,
                                                    int* __restrict__ anyUncut,
                                                    int* __restrict__ perm,
                                                    int* __restrict__ iperm,
                                                    int* __restrict__ counts) {
    __shared__ int s_badInt, s_badFloat;
    __shared__ int hist[17], off[18], cur[17];
    if (threadIdx.x == 0) { s_badInt = 0; s_badFloat = 0; *anyUncut = 0; }
    if (threadIdx.x < 17) hist[threadIdx.x] = 0;
    __syncthreads();
    int badI = 0, badF = 0;
    for (int i = threadIdx.x; i < 4096; i += 256) {
        unsigned int v = rin[i];
        if (v > 1u) badI = 1;
        if (v != 0u && v != 0x3f800000u) badF = 1;
    }
    if (badI) atomicOr(&s_badInt, 1);
    if (badF) atomicOr(&s_badFloat, 1);
    __syncthreads();
    const int fmt = (!s_badInt) ? 0 : ((!s_badFloat) ? 1 : 2);
    const unsigned char* rb = (const unsigned char*)rin;
    const float* rf = (const float*)rin;
    for (int i = threadIdx.x; i < Bn * Tn; i += 256) {
        unsigned char v;
        if (fmt == 0)      v = (unsigned char)(rin[i] != 0u);
        else if (fmt == 1) v = (unsigned char)(rf[i] != 0.0f);
        else               v = (unsigned char)(rb[i] != 0);
        r8[i] = v;
    }
    __syncthreads();
    int anyU = 0;
    for (int m = threadIdx.x; m < M2n; m += 256) {
        int c = m / Bn, b = m % Bn;
        int fr = Cn;
        for (int j = 0; j < Cn; j++) {
            if (r8[b * Tn + c * Cn + j]) { fr = j; break; }
        }
        firstReset[m] = fr;
        int ct = (fr < Cn);
        cut[m] = ct;
        if (!ct && c < NCn - 1) anyU = 1;
        atomicAdd(&hist[fr], 1);
    }
    if (anyU) atomicOr(anyUncut, 1);
    __syncthreads();
    if (threadIdx.x == 0) {
        off[16] = 0;
        for (int v = 15; v >= 0; v--) off[v] = off[v + 1] + hist[v + 1];
        for (int v = 0; v < 17; v++) cur[v] = (v == 16) ? 0 : off[v];
        for (int j = 0; j < 16; j++) counts[j] = off[j];
    }
    __syncthreads();
    for (int m = threadIdx.x; m < M2n; m += 256) {
        int fr = firstReset[m];
        int pos = atomicAdd(&cur[fr], 1);
        perm[pos] = m;
        iperm[m] = pos;
    }
}

// ---------------------------------------------------------------------------
// Split pre-passes (2-way hi/lo)
// ---------------------------------------------------------------------------
__global__ __launch_bounds__(256) void k_split_A2(const float* __restrict__ A,
                                                  unsigned short* __restrict__ a1,
                                                  unsigned short* __restrict__ a2) {
    size_t i = ((size_t)blockIdx.x * 256 + threadIdx.x) * 4;
    f32x4 v = *(const f32x4*)&A[i];
    us4 h1, h2;
#pragma unroll
    for (int e = 0; e < 4; e++) {
        unsigned short x1, x2;
        split2f(v[e], x1, x2);
        h1[e] = x1; h2[e] = x2;
    }
    *(us4*)&a1[i] = h1; *(us4*)&a2[i] = h2;
}

__global__ __launch_bounds__(256) void k_split_Bt(const float* __restrict__ Bm,
                                                  unsigned short* __restrict__ b1,
                                                  unsigned short* __restrict__ b2) {
    __shared__ float tile[64][65];
    const int k0 = blockIdx.y * 64, n0 = blockIdx.x * 64;
    const int c = threadIdx.x & 63, r4 = threadIdx.x >> 6;
#pragma unroll
    for (int i = 0; i < 16; i++) {
        int r = r4 * 16 + i;
        tile[r][c] = Bm[(size_t)(k0 + r) * Hn + n0 + c];
    }
    __syncthreads();
#pragma unroll
    for (int i = 0; i < 16; i++) {
        int r = r4 * 16 + i;
        float v = tile[c][r];                 // Bm[k0+c][n0+r]
        unsigned short x1, x2;
        split2f(v, x1, x2);
        b1[(size_t)(n0 + r) * Hn + k0 + c] = x1;
        b2[(size_t)(n0 + r) * Hn + k0 + c] = x2;
    }
}

__global__ __launch_bounds__(256) void k_split_X(const float* __restrict__ X,
                                                 unsigned short* __restrict__ x1,
                                                 unsigned short* __restrict__ x2) {
    size_t i = ((size_t)blockIdx.x * 256 + threadIdx.x) * 4;
    f32x4 v = *(const f32x4*)&X[i];
    us4 h1, h2;
#pragma unroll
    for (int e = 0; e < 4; e++) {
        unsigned short a, b;
        split2f(v[e], a, b);
        h1[e] = a; h2[e] = b;
    }
    *(us4*)&x1[i] = h1; *(us4*)&x2[i] = h2;
}

// ---------------------------------------------------------------------------
// Phase-1 GEMM: Out[m,n] = sum_k X[m,k]*Bt[n,k], 3 products.
// 256x128 tile, 512 threads (8 waves, 4m x 2n), FM=FN=4, BK=32, granule
// swizzle (conflict-free). PREX=1: 1-deep pipeline: read frags -> lgkmcnt(0)
// + barrier -> stage next tile (async DMA) -> MFMA (overlaps DMA) ->
// vmcnt(0) + barrier. Raw s_barrier, no compiler drain.
// Fused step0: rows with t%16==0 also write chunk-scan initial state splits.
// ---------------------------------------------------------------------------
template<int PREX>
__global__ __launch_bounds__(512) void k_gemm_p1(const unsigned short* __restrict__ X0,
                                                 const unsigned short* __restrict__ X1,
                                                 const unsigned short* __restrict__ B0,
                                                 const unsigned short* __restrict__ B1,
                                                 const float* __restrict__ Xf,
                                                 float* __restrict__ Out,
                                                 unsigned short* __restrict__ S0,
                                                 unsigned short* __restrict__ S1) {
    constexpr int BM = 256, BN = 128, LW = 32;
    __shared__ unsigned short ldsA[2 * BM * LW];   // 32 KB
    __shared__ unsigned short ldsB[2 * BN * LW];   // 16 KB
    const int tid = threadIdx.x;
    const int lane = tid & 63;
    const int wv = tid >> 6;
    const int wm = wv >> 1, wn = wv & 1;
    const int n0 = blockIdx.x * BN;
    const int m0 = blockIdx.y * BM;

    f4 acc[4][4];
#pragma unroll
    for (int fm = 0; fm < 4; fm++)
#pragma unroll
        for (int fn = 0; fn < 4; fn++) acc[fm][fn] = (f4){0.f, 0.f, 0.f, 0.f};

    const unsigned short* gA[4];
    unsigned short* lA[4];
    const float* gX[2];
    unsigned short* lX[2];
    const unsigned short* gB[2];
    unsigned short* lB[2];
    if constexpr (PREX) {
#pragma unroll
        for (int q = 0; q < 4; q++) {
            int u = tid + q * 512;                 // 2048 granules (16B each)
            int sp = u >> 10, row = (u >> 2) & 255, slot = u & 3;
            int g = slot ^ ((row >> 1) & 3);       // swizzled source granule
            gA[q] = (sp ? X1 : X0) + (size_t)(m0 + row) * Hn + g * 8;
            lA[q] = &ldsA[u * 8];                  // linear LDS dest
        }
    } else {
#pragma unroll
        for (int q = 0; q < 2; q++) {
            int u = tid + q * 512;                 // 1024 items (row x granule)
            int row = u >> 2, slot = u & 3;
            int s = slot ^ ((row >> 1) & 3);       // swizzled LDS slot
            gX[q] = Xf + (size_t)(m0 + row) * Hn + slot * 8;
            lX[q] = &ldsA[row * LW + s * 8];       // hi plane; lo at +BM*LW
        }
    }
#pragma unroll
    for (int q = 0; q < 2; q++) {
        int u = tid + q * 512;                     // 1024 granules
        int sp = u >> 9, row = (u >> 2) & 127, slot = u & 3;
        int g = slot ^ ((row >> 1) & 3);
        gB[q] = (sp ? B1 : B0) + (size_t)(n0 + row) * Hn + g * 8;
        lB[q] = &ldsB[u * 8];
    }
    const int sl = (lane >> 4) ^ ((lane >> 1) & 3);   // read-side slot per lane
    const int pa[3] = {0, 0, 1};
    const int pb[3] = {0, 1, 0};

    if constexpr (PREX) {
        // prologue: stage tile 0
#pragma unroll
        for (int q = 0; q < 4; q++) { GLOAD16(gA[q], lA[q]); gA[q] += 32; }
#pragma unroll
        for (int q = 0; q < 2; q++) { GLOAD16(gB[q], lB[q]); gB[q] += 32; }

        for (int k0 = 0; k0 < Hn; k0 += 32) {
            asm volatile("s_waitcnt vmcnt(0)" ::: "memory");
            __builtin_amdgcn_sched_barrier(0);
            __builtin_amdgcn_s_barrier();

            bf8 af[2][4], bfr[2][4];
#pragma unroll
            for (int sp = 0; sp < 2; sp++)
#pragma unroll
                for (int f = 0; f < 4; f++)
                    af[sp][f] = *(const bf8*)&ldsA[(sp * BM + wm * 64 + f * 16 + (lane & 15)) * LW + sl * 8];
#pragma unroll
            for (int sp = 0; sp < 2; sp++)
#pragma unroll
                for (int f = 0; f < 4; f++)
                    bfr[sp][f] = *(const bf8*)&ldsB[(sp * BN + wn * 64 + f * 16 + (lane & 15)) * LW + sl * 8];
            asm volatile("s_waitcnt lgkmcnt(0)" ::: "memory");
            __builtin_amdgcn_sched_barrier(0);
            __builtin_amdgcn_s_barrier();

            if (k0 + 32 < Hn) {
#pragma unroll
                for (int q = 0; q < 4; q++) { GLOAD16(gA[q], lA[q]); gA[q] += 32; }
#pragma unroll
                for (int q = 0; q < 2; q++) { GLOAD16(gB[q], lB[q]); gB[q] += 32; }
            }
            __builtin_amdgcn_sched_barrier(0);

#pragma unroll
            for (int p = 0; p < 3; p++)
#pragma unroll
                for (int fm = 0; fm < 4; fm++)
#pragma unroll
                    for (int fn = 0; fn < 4; fn++)
                        acc[fm][fn] = __builtin_amdgcn_mfma_f32_16x16x32_bf16(
                            af[pa[p]][fm], bfr[pb[p]][fn], acc[fm][fn], 0, 0, 0);
        }
    } else {
        for (int k0 = 0; k0 < Hn; k0 += 32) {
#pragma unroll
            for (int q = 0; q < 2; q++) {
                f32x4 va = *(const f32x4*)gX[q];
                f32x4 vb = *(const f32x4*)(gX[q] + 4);
                gX[q] += 32;
                us4 h1a, h2a, h1b, h2b;
#pragma unroll
                for (int e = 0; e < 4; e++) {
                    unsigned short p, r;
                    split2f(va[e], p, r); h1a[e] = p; h2a[e] = r;
                    split2f(vb[e], p, r); h1b[e] = p; h2b[e] = r;
                }
                *(us4*)lX[q] = h1a;
                *(us4*)(lX[q] + 4) = h1b;
                *(us4*)(lX[q] + BM * LW) = h2a;
                *(us4*)(lX[q] + BM * LW + 4) = h2b;
            }
#pragma unroll
            for (int q = 0; q < 2; q++) {
                GLOAD16(gB[q], lB[q]);
                gB[q] += 32;
            }
            __syncthreads();

            bf8 af[2][4], bfr[2][4];
#pragma unroll
            for (int sp = 0; sp < 2; sp++)
#pragma unroll
                for (int f = 0; f < 4; f++)
                    af[sp][f] = *(const bf8*)&ldsA[(sp * BM + wm * 64 + f * 16 + (lane & 15)) * LW + sl * 8];
#pragma unroll
            for (int sp = 0; sp < 2; sp++)
#pragma unroll
                for (int f = 0; f < 4; f++)
                    bfr[sp][f] = *(const bf8*)&ldsB[(sp * BN + wn * 64 + f * 16 + (lane & 15)) * LW + sl * 8];
#pragma unroll
            for (int p = 0; p < 3; p++)
#pragma unroll
                for (int fm = 0; fm < 4; fm++)
#pragma unroll
                    for (int fn = 0; fn < 4; fn++)
                        acc[fm][fn] = __builtin_amdgcn_mfma_f32_16x16x32_bf16(
                            af[pa[p]][fm], bfr[pb[p]][fn], acc[fm][fn], 0, 0, 0);
            __syncthreads();
        }
    }

    // D mapping: row=(lane>>4)*4+r, col=lane&15. Fused step0 for t%16==0 rows.
#pragma unroll
    for (int fm = 0; fm < 4; fm++)
#pragma unroll
        for (int r = 0; r < 4; r++) {
            int row = m0 + wm * 64 + fm * 16 + (lane >> 4) * 4 + r;
            int bb = row >> 11, t = row & 2047;
            int isC0 = ((t & 15) == 0);
            size_t ob = (size_t)row * Hn;
            size_t sb = (size_t)((t >> 4) * 8 + bb) * Hn;
#pragma unroll
            for (int fn = 0; fn < 4; fn++) {
                int n = n0 + wn * 64 + fn * 16 + (lane & 15);
                float v = acc[fm][fn][r];
                Out[ob + n] = v;
                if (isC0) {
                    unsigned short h1, h2;
                    split2f(v, h1, h2);
                    S0[sb + n] = h1; S1[sb + n] = h2;
                }
            }
        }
}

// ---------------------------------------------------------------------------
// Scan / correction GEMM: 64x64 tile, 256 threads (2x2 waves), FM=FN=2,
// BK=64, granule swizzle, 2-deep double-buffered pipeline with counted
// vmcnt(8): tile t computed while tile t+1 is in flight and tile t+2 is
// being staged. LDS 64 KB -> exactly 2 blocks/CU at grid 512.
// PHASE 2: v=(reset?0:acc)+Out; Out=v; split2 -> state.
// PHASE 3: as PHASE 2 (j=15) + carry: u-splits at iperm[m+8], fp32 Hin[m+8].
// PHASE 4: correction on sorted alive prefix.
// ---------------------------------------------------------------------------
template<int PHASE>
__global__ __launch_bounds__(256) void k_gemm_s(const unsigned short* __restrict__ S0,
                                                const unsigned short* __restrict__ S1,
                                                const unsigned short* __restrict__ W0,
                                                const unsigned short* __restrict__ W1,
                                                float* __restrict__ Out,
                                                unsigned short* __restrict__ O0,
                                                unsigned short* __restrict__ O1,
                                                const unsigned char* __restrict__ r8v,
                                                const int* __restrict__ perm,
                                                const int* __restrict__ iperm,
                                                const int* __restrict__ counts,
                                                unsigned short* __restrict__ U0,
                                                unsigned short* __restrict__ U1,
                                                float* __restrict__ Hin,
                                                int j) {
    constexpr int BM = 64, BN = 64, BK = 64;
    constexpr int TSZ = 2 * BM * BK;               // shorts per tile buffer (8192)
    constexpr int NT = Hn / BK;                    // 32 k-tiles
    __shared__ unsigned short ldsA[2 * TSZ];       // 32 KB (2 bufs)
    __shared__ unsigned short ldsB[2 * TSZ];       // 32 KB
    const int tid = threadIdx.x;
    const int lane = tid & 63;
    const int wv = tid >> 6;
    const int wm = wv >> 1, wn = wv & 1;
    const int n0 = blockIdx.x * BN;
    const int m0 = blockIdx.y * BM;

    int cnt = 0;
    if constexpr (PHASE == 4) {
        cnt = counts[j];
        if (m0 >= cnt) return;
    }

    f4 acc[2][2];
#pragma unroll
    for (int fm = 0; fm < 2; fm++)
#pragma unroll
        for (int fn = 0; fn < 2; fn++) acc[fm][fn] = (f4){0.f, 0.f, 0.f, 0.f};

    const unsigned short* gA[4];
    unsigned short* lA[4];
    const unsigned short* gB[4];
    unsigned short* lB[4];
#pragma unroll
    for (int q = 0; q < 4; q++) {
        int u = tid + q * 256;                     // 1024 granules per operand
        int sp = u >> 9, row = (u >> 3) & 63, s = u & 7;
        int g = s ^ (row & 7);                     // swizzled source granule
        gA[q] = (sp ? S1 : S0) + (size_t)(m0 + row) * Hn + g * 8;
        lA[q] = &ldsA[u * 8];
        gB[q] = (sp ? W1 : W0) + (size_t)(n0 + row) * Hn + g * 8;
        lB[q] = &ldsB[u * 8];
    }
    const int pa[3] = {0, 0, 1};
    const int pb[3] = {0, 1, 0};

#define STAGE_S(bsel)                                                        \
    {                                                                        \
        const int boff_ = (bsel) * TSZ;                                      \
        _Pragma("unroll")                                                    \
        for (int q = 0; q < 4; q++) {                                        \
            GLOAD16(gA[q], lA[q] + boff_);                                   \
            GLOAD16(gB[q], lB[q] + boff_);                                   \
            gA[q] += BK; gB[q] += BK;                                        \
        }                                                                    \
    }

    // prologue: stage tiles 0 and 1
    STAGE_S(0);
    STAGE_S(1);

    for (int t = 0; t < NT; t++) {
        if (t == NT - 1) { asm volatile("s_waitcnt vmcnt(0)" ::: "memory"); }
        else             { asm volatile("s_waitcnt vmcnt(8)" ::: "memory"); }
        __builtin_amdgcn_sched_barrier(0);
        __builtin_amdgcn_s_barrier();

        const unsigned short* curA = &ldsA[(t & 1) * TSZ];
        const unsigned short* curB = &ldsB[(t & 1) * TSZ];
        bf8 af[2][2][2], bfr[2][2][2];             // [h][sp][f]
#pragma unroll
        for (int h = 0; h < 2; h++) {
            const int slh = ((h * 4) + (lane >> 4)) ^ (lane & 7);
#pragma unroll
            for (int sp = 0; sp < 2; sp++)
#pragma unroll
                for (int f = 0; f < 2; f++) {
                    af[h][sp][f] = *(const bf8*)&curA[(sp * BM + wm * 32 + f * 16 + (lane & 15)) * BK + slh * 8];
                    bfr[h][sp][f] = *(const bf8*)&curB[(sp * BN + wn * 32 + f * 16 + (lane & 15)) * BK + slh * 8];
                }
        }
        asm volatile("s_waitcnt lgkmcnt(0)" ::: "memory");
        __builtin_amdgcn_sched_barrier(0);
        __builtin_amdgcn_s_barrier();

        if (t + 2 < NT) STAGE_S(t & 1);
        __builtin_amdgcn_sched_barrier(0);

#pragma unroll
        for (int h = 0; h < 2; h++)
#pragma unroll
            for (int p = 0; p < 3; p++)
#pragma unroll
                for (int fm = 0; fm < 2; fm++)
#pragma unroll
                    for (int fn = 0; fn < 2; fn++)
                        acc[fm][fn] = __builtin_amdgcn_mfma_f32_16x16x32_bf16(
                            af[h][pa[p]][fm], bfr[h][pb[p]][fn], acc[fm][fn], 0, 0, 0);
    }
#undef STAGE_S

    if constexpr (PHASE == 2 || PHASE == 3) {
#pragma unroll
        for (int fm = 0; fm < 2; fm++)
#pragma unroll
            for (int r = 0; r < 4; r++) {
                int m = m0 + wm * 32 + fm * 16 + (lane >> 4) * 4 + r;
                int cch = m >> 3, bb = m & 7;
                int t = cch * Cn + j;
                int rfl = r8v[bb * Tn + t];
                size_t ob = ((size_t)bb * Tn + t) * (size_t)Hn;
                size_t sb = (size_t)m * Hn;
                int carry = 0;
                size_t ub = 0, hb = 0;
                if constexpr (PHASE == 3) {
                    carry = (m < M2n - 8);
                    if (carry) {
                        ub = (size_t)iperm[m + 8] * Hn;
                        hb = (size_t)(m + 8) * Hn;
                    }
                }
#pragma unroll
                for (int fn = 0; fn < 2; fn++) {
                    int n = n0 + wn * 32 + fn * 16 + (lane & 15);
                    float v = (rfl ? 0.0f : acc[fm][fn][r]) + Out[ob + n];
                    Out[ob + n] = v;
                    unsigned short h1, h2;
                    split2f(v, h1, h2);
                    O0[sb + n] = h1; O1[sb + n] = h2;
                    if constexpr (PHASE == 3) {
                        if (carry) {
                            U0[ub + n] = h1; U1[ub + n] = h2;
                            Hin[hb + n] = v;
                        }
                    }
                }
            }
    } else {  // PHASE 4 (sorted prefix)
#pragma unroll
        for (int fm = 0; fm < 2; fm++)
#pragma unroll
            for (int r = 0; r < 4; r++) {
                int s = m0 + wm * 32 + fm * 16 + (lane >> 4) * 4 + r;
                int alive = (s < cnt);
                int m = perm[s];
                int cch = m >> 3, bb = m & 7;
                int t = cch * Cn + j;
                size_t ob = ((size_t)bb * Tn + t) * (size_t)Hn;
                size_t sb = (size_t)s * Hn;
#pragma unroll
                for (int fn = 0; fn < 2; fn++) {
                    int n = n0 + wn * 32 + fn * 16 + (lane & 15);
                    if (alive) {
                        float val = acc[fm][fn][r];
                        unsigned short h1, h2;
                        split2f(val, h1, h2);
                        O0[sb + n] = h1; O1[sb + n] = h2;
                        Out[ob + n] += val;
                    }
                }
            }
    }
}

// ---------------------------------------------------------------------------
// Zero carry state for chunk-0 rows (sorted positions iperm[0..7]) + Hin rows.
// ---------------------------------------------------------------------------
__global__ __launch_bounds__(256) void k_zero_c0(const int* __restrict__ iperm,
                                                 unsigned short* __restrict__ U0,
                                                 unsigned short* __restrict__ U1,
                                                 float* __restrict__ Hin) {
    int b = blockIdx.x;
    int s = iperm[b];
    for (int n = threadIdx.x; n < Hn; n += 256) {
        U0[(size_t)s * Hn + n] = 0;
        U1[(size_t)s * Hn + n] = 0;
        Hin[(size_t)b * Hn + n] = 0.0f;
    }
}

// ---------------------------------------------------------------------------
// Exact fallback for uncut chunks (E[occurrences] ~ 0.016).
// ---------------------------------------------------------------------------
__global__ __launch_bounds__(1024) void k_fallback(float* __restrict__ Hin,
                                                   const float* __restrict__ A,
                                                   const int* __restrict__ cut,
                                                   const int* __restrict__ anyUncut,
                                                   unsigned short* __restrict__ u1,
                                                   unsigned short* __restrict__ u2,
                                                   const int* __restrict__ iperm) {
    if (*anyUncut == 0) return;
    __shared__ float v0[Hn];
    __shared__ float v1[Hn];
    for (int c = 1; c < NCn; c++) {
        for (int b = 0; b < Bn; b++) {
            if (cut[(c - 1) * Bn + b]) continue;
            for (int n = threadIdx.x; n < Hn; n += 1024)
                v0[n] = Hin[((size_t)(c - 1) * Bn + b) * Hn + n];
            __syncthreads();
            for (int s = 0; s < Cn; s++) {
                float* pin = (s & 1) ? v1 : v0;
                float* pout = (s & 1) ? v0 : v1;
                for (int n = threadIdx.x; n < Hn; n += 1024) {
                    float accv = 0.0f;
                    const float* Ar = &A[(size_t)n * Hn];
                    for (int k = 0; k < Hn; k++) accv += pin[k] * Ar[k];
                    pout[n] = accv;
                }
                __syncthreads();
            }
            float* pres = (Cn & 1) ? v1 : v0;
            int mrow = c * Bn + b;
            size_t dst = (size_t)mrow * Hn;
            size_t sdst = (size_t)iperm[mrow] * Hn;
            for (int n = threadIdx.x; n < Hn; n += 1024) {
                float nv = Hin[dst + n] + pres[n];
                Hin[dst + n] = nv;
                unsigned short h1, h2;
                split2f(nv, h1, h2);
                u1[sdst + n] = h1; u2[sdst + n] = h2;
            }
            __syncthreads();
        }
    }
}

extern "C" void kernel_launch(void* const* d_in, const int* in_sizes, int n_in,
                              void* d_out, int out_size, void* d_ws, size_t ws_size,
                              hipStream_t stream) {
    const float* x = (const float*)d_in[0];
    const unsigned int* rst = (const unsigned int*)d_in[1];
    const float* Am = (const float*)d_in[2];
    const float* Bm = (const float*)d_in[3];
    float* Out = (float*)d_out;
    char* ws = (char*)d_ws;

    unsigned char* r8 = (unsigned char*)ws;                 // 16 KB
    int* cut = (int*)(ws + 16384);
    int* firstReset = (int*)(ws + 20480);
    int* perm = (int*)(ws + 24576);
    int* iperm = (int*)(ws + 28672);
    int* counts = (int*)(ws + 32768);
    int* anyUncut = (int*)(ws + 32832);
    unsigned short* a1 = (unsigned short*)(ws + 65536);     // A splits [n][k], 8MB ea
    unsigned short* a2 = a1 + 4194304;
    unsigned short* b1 = a2 + 4194304;                      // Bt splits [n][k], 8MB ea
    unsigned short* b2 = b1 + 4194304;
    unsigned short* sP1 = b2 + 4194304;                     // state splits, 4MB ea
    unsigned short* sP2 = sP1 + 2097152;
    unsigned short* sQ1 = sP2 + 2097152;
    unsigned short* sQ2 = sQ1 + 2097152;
    unsigned short* uP1 = sQ2 + 2097152;                    // carry u splits, 4MB ea
    unsigned short* uP2 = uP1 + 2097152;
    float* Hin = (float*)(uP2 + 2097152);                   // 8MB fp32
    unsigned short* x1 = (unsigned short*)(Hin + 2097152);  // X splits, 67MB ea
    unsigned short* x2 = x1 + 33554432;
    const size_t NEED_X = 201392128ull;
    const bool prex = (ws_size >= NEED_X);

    k_reset_prep<<<1, 256, 0, stream>>>(rst, r8, cut, firstReset, anyUncut, perm, iperm, counts);
    k_split_A2<<<4096, 256, 0, stream>>>(Am, a1, a2);
    k_split_Bt<<<dim3(32, 32), 256, 0, stream>>>(Bm, b1, b2);

    // Phase 1: bx = x @ B  (fused step0 -> sP)
    if (prex) {
        k_split_X<<<32768, 256, 0, stream>>>(x, x1, x2);
        k_gemm_p1<1><<<dim3(Hn / 128, (Bn * Tn) / 256), 512, 0, stream>>>(
            x1, x2, b1, b2, nullptr, Out, sP1, sP2);
    } else {
        k_gemm_p1<0><<<dim3(Hn / 128, (Bn * Tn) / 256), 512, 0, stream>>>(
            nullptr, nullptr, b1, b2, x, Out, sP1, sP2);
    }

    // Phase 2: chunk-local scans (j=15 carries h_in into uP/Hin)
    for (int j = 1; j < Cn; j++) {
        const unsigned short* i1 = (j & 1) ? sP1 : sQ1;
        const unsigned short* i2 = (j & 1) ? sP2 : sQ2;
        unsigned short* o1 = (j & 1) ? sQ1 : sP1;
        unsigned short* o2 = (j & 1) ? sQ2 : sP2;
        if (j < Cn - 1) {
            k_gemm_s<2><<<dim3(Hn / 64, M2n / 64), 256, 0, stream>>>(
                i1, i2, a1, a2, Out, o1, o2, r8, nullptr, nullptr, nullptr,
                nullptr, nullptr, nullptr, j);
        } else {
            k_gemm_s<3><<<dim3(Hn / 64, M2n / 64), 256, 0, stream>>>(
                i1, i2, a1, a2, Out, o1, o2, r8, nullptr, iperm, nullptr,
                uP1, uP2, Hin, j);
        }
    }

    // Phase 3: chunk-0 carry zero + exact fallback for uncut chunks
    k_zero_c0<<<8, 256, 0, stream>>>(iperm, uP1, uP2, Hin);
    k_fallback<<<1, 1024, 0, stream>>>(Hin, Am, cut, anyUncut, uP1, uP2, iperm);

    // Phase 4: corrections on shrinking sorted prefix
    for (int j = 0; j < Cn; j++) {
        const unsigned short* i1 = (j == 0) ? uP1 : ((j & 1) ? sP1 : sQ1);
        const unsigned short* i2 = (j == 0) ? uP2 : ((j & 1) ? sP2 : sQ2);
        unsigned short* o1 = (j & 1) ? sQ1 : sP1;
        unsigned short* o2 = (j & 1) ? sQ2 : sP2;
        k_gemm_s<4><<<dim3(Hn / 64, M2n / 64), 256, 0, stream>>>(
            i1, i2, a1, a2, Out, o1, o2, nullptr, perm, nullptr, counts,
            nullptr, nullptr, nullptr, j);
    }
}

// Round 8
// 1235.884 us; speedup vs baseline: 1.6314x; 1.0419x over previous
//
#include <hip/hip_runtime.h>

#define Hn 2048
#define Bn 8
#define Tn 2048
#define Cn 16
#define NCn (Tn / Cn)     // 128 chunks
#define M2n (NCn * Bn)    // 1024 scan rows

using f32x4 = __attribute__((ext_vector_type(4))) float;
using u32x4 = __attribute__((ext_vector_type(4))) unsigned int;
using us4   = __attribute__((ext_vector_type(4))) unsigned short;
using bf8   = __attribute__((ext_vector_type(8))) short;
using f4    = __attribute__((ext_vector_type(4))) float;

#define GLOAD16(g, l) __builtin_amdgcn_global_load_lds(                      \
    (const __attribute__((address_space(1))) void*)(g),                      \
    (__attribute__((address_space(3))) void*)(l), 16, 0, 0)

__device__ __forceinline__ unsigned short f2bf(float f) {
    unsigned u = __builtin_bit_cast(unsigned, f);
    u = u + 0x7fffu + ((u >> 16) & 1u);
    return (unsigned short)(u >> 16);
}
__device__ __forceinline__ float bf2f(unsigned short h) {
    unsigned u = ((unsigned)h) << 16;
    return __builtin_bit_cast(float, u);
}
__device__ __forceinline__ void split2f(float v, unsigned short& a, unsigned short& b) {
    a = f2bf(v);
    b = f2bf(v - bf2f(a));
}

// ---------------------------------------------------------------------------
// Mega-prep kernel (single launch, block-range dispatch):
//  [0, 4096)            : A 2-way split
//  [4096, 5120)         : B^T 2-way split (transpose)
//  [5120]               : reset canonicalize + counting sort
//  [5121, 5121+32768)   : X 2-way split (only when prex grid launched)
// ---------------------------------------------------------------------------
__global__ __launch_bounds__(256) void k_prep(const float* __restrict__ A,
                                              unsigned short* __restrict__ a1,
                                              unsigned short* __restrict__ a2,
                                              const float* __restrict__ Bm,
                                              unsigned short* __restrict__ b1,
                                              unsigned short* __restrict__ b2,
                                              const float* __restrict__ X,
                                              unsigned short* __restrict__ x1,
                                              unsigned short* __restrict__ x2,
                                              const unsigned int* __restrict__ rin,
                                              unsigned char* __restrict__ r8,
                                              int* __restrict__ cut,
                                              int* __restrict__ firstReset,
                                              int* __restrict__ anyUncut,
                                              int* __restrict__ perm,
                                              int* __restrict__ iperm,
                                              int* __restrict__ counts) {
    const int bid = blockIdx.x;
    if (bid < 4096) {
        // ---- A split ----
        size_t i = ((size_t)bid * 256 + threadIdx.x) * 4;
        f32x4 v = *(const f32x4*)&A[i];
        us4 h1, h2;
#pragma unroll
        for (int e = 0; e < 4; e++) {
            unsigned short p, r;
            split2f(v[e], p, r);
            h1[e] = p; h2[e] = r;
        }
        *(us4*)&a1[i] = h1; *(us4*)&a2[i] = h2;
        return;
    }
    if (bid < 5120) {
        // ---- B^T split ----
        __shared__ float tile[64][65];
        int t = bid - 4096;
        const int k0 = (t >> 5) * 64, n0 = (t & 31) * 64;
        const int c = threadIdx.x & 63, r4 = threadIdx.x >> 6;
#pragma unroll
        for (int i = 0; i < 16; i++) {
            int r = r4 * 16 + i;
            tile[r][c] = Bm[(size_t)(k0 + r) * Hn + n0 + c];
        }
        __syncthreads();
#pragma unroll
        for (int i = 0; i < 16; i++) {
            int r = r4 * 16 + i;
            float v = tile[c][r];
            unsigned short p, q;
            split2f(v, p, q);
            b1[(size_t)(n0 + r) * Hn + k0 + c] = p;
            b2[(size_t)(n0 + r) * Hn + k0 + c] = q;
        }
        return;
    }
    if (bid == 5120) {
        // ---- reset prep ----
        __shared__ int s_badInt, s_badFloat;
        __shared__ int hist[17], off[18], cur[17];
        if (threadIdx.x == 0) { s_badInt = 0; s_badFloat = 0; *anyUncut = 0; }
        if (threadIdx.x < 17) hist[threadIdx.x] = 0;
        __syncthreads();
        int badI = 0, badF = 0;
        for (int i = threadIdx.x; i < 4096; i += 256) {
            unsigned int v = rin[i];
            if (v > 1u) badI = 1;
            if (v != 0u && v != 0x3f800000u) badF = 1;
        }
        if (badI) atomicOr(&s_badInt, 1);
        if (badF) atomicOr(&s_badFloat, 1);
        __syncthreads();
        const int fmt = (!s_badInt) ? 0 : ((!s_badFloat) ? 1 : 2);
        const unsigned char* rb = (const unsigned char*)rin;
        const float* rf = (const float*)rin;
        for (int i = threadIdx.x; i < Bn * Tn; i += 256) {
            unsigned char v;
            if (fmt == 0)      v = (unsigned char)(rin[i] != 0u);
            else if (fmt == 1) v = (unsigned char)(rf[i] != 0.0f);
            else               v = (unsigned char)(rb[i] != 0);
            r8[i] = v;
        }
        __syncthreads();
        int anyU = 0;
        for (int m = threadIdx.x; m < M2n; m += 256) {
            int c = m / Bn, b = m % Bn;
            int fr = Cn;
            for (int j = 0; j < Cn; j++) {
                if (r8[b * Tn + c * Cn + j]) { fr = j; break; }
            }
            firstReset[m] = fr;
            int ct = (fr < Cn);
            cut[m] = ct;
            if (!ct && c < NCn - 1) anyU = 1;
            atomicAdd(&hist[fr], 1);
        }
        if (anyU) atomicOr(anyUncut, 1);
        __syncthreads();
        if (threadIdx.x == 0) {
            off[16] = 0;
            for (int v = 15; v >= 0; v--) off[v] = off[v + 1] + hist[v + 1];
            for (int v = 0; v < 17; v++) cur[v] = (v == 16) ? 0 : off[v];
            for (int j = 0; j < 16; j++) counts[j] = off[j];
        }
        __syncthreads();
        for (int m = threadIdx.x; m < M2n; m += 256) {
            int fr = firstReset[m];
            int pos = atomicAdd(&cur[fr], 1);
            perm[pos] = m;
            iperm[m] = pos;
        }
        return;
    }
    // ---- X split ----
    {
        size_t i = ((size_t)(bid - 5121) * 256 + threadIdx.x) * 4;
        f32x4 v = *(const f32x4*)&X[i];
        us4 h1, h2;
#pragma unroll
        for (int e = 0; e < 4; e++) {
            unsigned short p, r;
            split2f(v[e], p, r);
            h1[e] = p; h2[e] = r;
        }
        *(us4*)&x1[i] = h1; *(us4*)&x2[i] = h2;
    }
}

// ---------------------------------------------------------------------------
// Phase-1 GEMM: Out[m,n] = sum_k X[m,k]*Bt[n,k], 3 products.
// 256x128 tile, 512 threads (8 waves, 4m x 2n), FM=FN=4, BK=32, granule
// swizzle (conflict-free), global_load_lds staging, simple 2-barrier loop
// (R6-proven). Fused step0 for t%16==0 rows.
// ---------------------------------------------------------------------------
template<int PREX>
__global__ __launch_bounds__(512) void k_gemm_p1(const unsigned short* __restrict__ X0,
                                                 const unsigned short* __restrict__ X1,
                                                 const unsigned short* __restrict__ B0,
                                                 const unsigned short* __restrict__ B1,
                                                 const float* __restrict__ Xf,
                                                 float* __restrict__ Out,
                                                 unsigned short* __restrict__ S0,
                                                 unsigned short* __restrict__ S1) {
    constexpr int BM = 256, BN = 128, LW = 32;
    __shared__ unsigned short ldsA[2 * BM * LW];   // 32 KB
    __shared__ unsigned short ldsB[2 * BN * LW];   // 16 KB
    const int tid = threadIdx.x;
    const int lane = tid & 63;
    const int wv = tid >> 6;
    const int wm = wv >> 1, wn = wv & 1;
    const int n0 = blockIdx.x * BN;
    const int m0 = blockIdx.y * BM;

    f4 acc[4][4];
#pragma unroll
    for (int fm = 0; fm < 4; fm++)
#pragma unroll
        for (int fn = 0; fn < 4; fn++) acc[fm][fn] = (f4){0.f, 0.f, 0.f, 0.f};

    const unsigned short* gA[4];
    unsigned short* lA[4];
    const float* gX[2];
    unsigned short* lX[2];
    const unsigned short* gB[2];
    unsigned short* lB[2];
    if constexpr (PREX) {
#pragma unroll
        for (int q = 0; q < 4; q++) {
            int u = tid + q * 512;                 // 2048 granules (16B each)
            int sp = u >> 10, row = (u >> 2) & 255, slot = u & 3;
            int g = slot ^ ((row >> 1) & 3);       // swizzled source granule
            gA[q] = (sp ? X1 : X0) + (size_t)(m0 + row) * Hn + g * 8;
            lA[q] = &ldsA[u * 8];                  // linear LDS dest
        }
    } else {
#pragma unroll
        for (int q = 0; q < 2; q++) {
            int u = tid + q * 512;                 // 1024 items (row x granule)
            int row = u >> 2, slot = u & 3;
            int s = slot ^ ((row >> 1) & 3);       // swizzled LDS slot
            gX[q] = Xf + (size_t)(m0 + row) * Hn + slot * 8;
            lX[q] = &ldsA[row * LW + s * 8];       // hi plane; lo at +BM*LW
        }
    }
#pragma unroll
    for (int q = 0; q < 2; q++) {
        int u = tid + q * 512;                     // 1024 granules
        int sp = u >> 9, row = (u >> 2) & 127, slot = u & 3;
        int g = slot ^ ((row >> 1) & 3);
        gB[q] = (sp ? B1 : B0) + (size_t)(n0 + row) * Hn + g * 8;
        lB[q] = &ldsB[u * 8];
    }
    const int sl = (lane >> 4) ^ ((lane >> 1) & 3);   // read-side slot per lane
    const int pa[3] = {0, 0, 1};
    const int pb[3] = {0, 1, 0};

    for (int k0 = 0; k0 < Hn; k0 += 32) {
        if constexpr (PREX) {
#pragma unroll
            for (int q = 0; q < 4; q++) {
                GLOAD16(gA[q], lA[q]);
                gA[q] += 32;
            }
        } else {
#pragma unroll
            for (int q = 0; q < 2; q++) {
                f32x4 va = *(const f32x4*)gX[q];
                f32x4 vb = *(const f32x4*)(gX[q] + 4);
                gX[q] += 32;
                us4 h1a, h2a, h1b, h2b;
#pragma unroll
                for (int e = 0; e < 4; e++) {
                    unsigned short p, r;
                    split2f(va[e], p, r); h1a[e] = p; h2a[e] = r;
                    split2f(vb[e], p, r); h1b[e] = p; h2b[e] = r;
                }
                *(us4*)lX[q] = h1a;
                *(us4*)(lX[q] + 4) = h1b;
                *(us4*)(lX[q] + BM * LW) = h2a;
                *(us4*)(lX[q] + BM * LW + 4) = h2b;
            }
        }
#pragma unroll
        for (int q = 0; q < 2; q++) {
            GLOAD16(gB[q], lB[q]);
            gB[q] += 32;
        }
        __syncthreads();   // drains vmcnt(0): DMA staging complete

        bf8 af[2][4], bfr[2][4];
#pragma unroll
        for (int sp = 0; sp < 2; sp++)
#pragma unroll
            for (int f = 0; f < 4; f++)
                af[sp][f] = *(const bf8*)&ldsA[(sp * BM + wm * 64 + f * 16 + (lane & 15)) * LW + sl * 8];
#pragma unroll
        for (int sp = 0; sp < 2; sp++)
#pragma unroll
            for (int f = 0; f < 4; f++)
                bfr[sp][f] = *(const bf8*)&ldsB[(sp * BN + wn * 64 + f * 16 + (lane & 15)) * LW + sl * 8];

#pragma unroll
        for (int p = 0; p < 3; p++)
#pragma unroll
            for (int fm = 0; fm < 4; fm++)
#pragma unroll
                for (int fn = 0; fn < 4; fn++)
                    acc[fm][fn] = __builtin_amdgcn_mfma_f32_16x16x32_bf16(
                        af[pa[p]][fm], bfr[pb[p]][fn], acc[fm][fn], 0, 0, 0);
        __syncthreads();   // protect LDS reuse before next stage
    }

    // D mapping: row=(lane>>4)*4+r, col=lane&15. Fused step0 for t%16==0 rows.
#pragma unroll
    for (int fm = 0; fm < 4; fm++)
#pragma unroll
        for (int r = 0; r < 4; r++) {
            int row = m0 + wm * 64 + fm * 16 + (lane >> 4) * 4 + r;
            int bb = row >> 11, t = row & 2047;
            int isC0 = ((t & 15) == 0);
            size_t ob = (size_t)row * Hn;
            size_t sb = (size_t)((t >> 4) * 8 + bb) * Hn;
#pragma unroll
            for (int fn = 0; fn < 4; fn++) {
                int n = n0 + wn * 64 + fn * 16 + (lane & 15);
                float v = acc[fm][fn][r];
                Out[ob + n] = v;
                if (isC0) {
                    unsigned short h1, h2;
                    split2f(v, h1, h2);
                    S0[sb + n] = h1; S1[sb + n] = h2;
                }
            }
        }
}

// ---------------------------------------------------------------------------
// Scan / correction GEMM: 64x64 tile, 256 threads (2x2 waves), FM=FN=2,
// BK=64, granule swizzle, 2-deep double-buffered pipeline with counted
// vmcnt(8); s_setprio(1) around MFMA cluster (T5).
// PHASE 2: v=(reset?0:acc)+Out; Out=v; split2 -> state.
// PHASE 3: as PHASE 2 (j=15) + carry u at iperm[m+8] + Hin[m+8]; zeroes
//          chunk-0 carry rows (m<8) inline.
// PHASE 4: correction on sorted alive prefix.
// ---------------------------------------------------------------------------
template<int PHASE>
__global__ __launch_bounds__(256) void k_gemm_s(const unsigned short* __restrict__ S0,
                                                const unsigned short* __restrict__ S1,
                                                const unsigned short* __restrict__ W0,
                                                const unsigned short* __restrict__ W1,
                                                float* __restrict__ Out,
                                                unsigned short* __restrict__ O0,
                                                unsigned short* __restrict__ O1,
                                                const unsigned char* __restrict__ r8v,
                                                const int* __restrict__ perm,
                                                const int* __restrict__ iperm,
                                                const int* __restrict__ counts,
                                                unsigned short* __restrict__ U0,
                                                unsigned short* __restrict__ U1,
                                                float* __restrict__ Hin,
                                                int j) {
    constexpr int BM = 64, BN = 64, BK = 64;
    constexpr int TSZ = 2 * BM * BK;               // shorts per tile buffer (8192)
    constexpr int NT = Hn / BK;                    // 32 k-tiles
    __shared__ unsigned short ldsA[2 * TSZ];       // 32 KB (2 bufs)
    __shared__ unsigned short ldsB[2 * TSZ];       // 32 KB
    const int tid = threadIdx.x;
    const int lane = tid & 63;
    const int wv = tid >> 6;
    const int wm = wv >> 1, wn = wv & 1;
    const int n0 = blockIdx.x * BN;
    const int m0 = blockIdx.y * BM;

    int cnt = 0;
    if constexpr (PHASE == 4) {
        cnt = counts[j];
        if (m0 >= cnt) return;
    }

    f4 acc[2][2];
#pragma unroll
    for (int fm = 0; fm < 2; fm++)
#pragma unroll
        for (int fn = 0; fn < 2; fn++) acc[fm][fn] = (f4){0.f, 0.f, 0.f, 0.f};

    const unsigned short* gA[4];
    unsigned short* lA[4];
    const unsigned short* gB[4];
    unsigned short* lB[4];
#pragma unroll
    for (int q = 0; q < 4; q++) {
        int u = tid + q * 256;                     // 1024 granules per operand
        int sp = u >> 9, row = (u >> 3) & 63, s = u & 7;
        int g = s ^ (row & 7);                     // swizzled source granule
        gA[q] = (sp ? S1 : S0) + (size_t)(m0 + row) * Hn + g * 8;
        lA[q] = &ldsA[u * 8];
        gB[q] = (sp ? W1 : W0) + (size_t)(n0 + row) * Hn + g * 8;
        lB[q] = &ldsB[u * 8];
    }
    const int pa[3] = {0, 0, 1};
    const int pb[3] = {0, 1, 0};

#define STAGE_S(bsel)                                                        \
    {                                                                        \
        const int boff_ = (bsel) * TSZ;                                      \
        _Pragma("unroll")                                                    \
        for (int q = 0; q < 4; q++) {                                        \
            GLOAD16(gA[q], lA[q] + boff_);                                   \
            GLOAD16(gB[q], lB[q] + boff_);                                   \
            gA[q] += BK; gB[q] += BK;                                        \
        }                                                                    \
    }

    // prologue: stage tiles 0 and 1
    STAGE_S(0);
    STAGE_S(1);

    for (int t = 0; t < NT; t++) {
        if (t == NT - 1) { asm volatile("s_waitcnt vmcnt(0)" ::: "memory"); }
        else             { asm volatile("s_waitcnt vmcnt(8)" ::: "memory"); }
        __builtin_amdgcn_sched_barrier(0);
        __builtin_amdgcn_s_barrier();

        const unsigned short* curA = &ldsA[(t & 1) * TSZ];
        const unsigned short* curB = &ldsB[(t & 1) * TSZ];
        bf8 af[2][2][2], bfr[2][2][2];             // [h][sp][f]
#pragma unroll
        for (int h = 0; h < 2; h++) {
            const int slh = ((h * 4) + (lane >> 4)) ^ (lane & 7);
#pragma unroll
            for (int sp = 0; sp < 2; sp++)
#pragma unroll
                for (int f = 0; f < 2; f++) {
                    af[h][sp][f] = *(const bf8*)&curA[(sp * BM + wm * 32 + f * 16 + (lane & 15)) * BK + slh * 8];
                    bfr[h][sp][f] = *(const bf8*)&curB[(sp * BN + wn * 32 + f * 16 + (lane & 15)) * BK + slh * 8];
                }
        }
        asm volatile("s_waitcnt lgkmcnt(0)" ::: "memory");
        __builtin_amdgcn_sched_barrier(0);
        __builtin_amdgcn_s_barrier();

        if (t + 2 < NT) STAGE_S(t & 1);
        __builtin_amdgcn_sched_barrier(0);

        __builtin_amdgcn_s_setprio(1);
#pragma unroll
        for (int h = 0; h < 2; h++)
#pragma unroll
            for (int p = 0; p < 3; p++)
#pragma unroll
                for (int fm = 0; fm < 2; fm++)
#pragma unroll
                    for (int fn = 0; fn < 2; fn++)
                        acc[fm][fn] = __builtin_amdgcn_mfma_f32_16x16x32_bf16(
                            af[h][pa[p]][fm], bfr[h][pb[p]][fn], acc[fm][fn], 0, 0, 0);
        __builtin_amdgcn_s_setprio(0);
    }
#undef STAGE_S

    if constexpr (PHASE == 2 || PHASE == 3) {
#pragma unroll
        for (int fm = 0; fm < 2; fm++)
#pragma unroll
            for (int r = 0; r < 4; r++) {
                int m = m0 + wm * 32 + fm * 16 + (lane >> 4) * 4 + r;
                int cch = m >> 3, bb = m & 7;
                int t = cch * Cn + j;
                int rfl = r8v[bb * Tn + t];
                size_t ob = ((size_t)bb * Tn + t) * (size_t)Hn;
                size_t sb = (size_t)m * Hn;
                int carry = 0;
                size_t ub = 0, hb = 0;
                if constexpr (PHASE == 3) {
                    carry = (m < M2n - 8);
                    if (carry) {
                        ub = (size_t)iperm[m + 8] * Hn;
                        hb = (size_t)(m + 8) * Hn;
                    }
                }
#pragma unroll
                for (int fn = 0; fn < 2; fn++) {
                    int n = n0 + wn * 32 + fn * 16 + (lane & 15);
                    float v = (rfl ? 0.0f : acc[fm][fn][r]) + Out[ob + n];
                    Out[ob + n] = v;
                    unsigned short h1, h2;
                    split2f(v, h1, h2);
                    O0[sb + n] = h1; O1[sb + n] = h2;
                    if constexpr (PHASE == 3) {
                        if (carry) {
                            U0[ub + n] = h1; U1[ub + n] = h2;
                            Hin[hb + n] = v;
                        }
                        if (m < 8) {                       // chunk-0 carry = 0
                            size_t zb = (size_t)iperm[m] * Hn;
                            U0[zb + n] = 0; U1[zb + n] = 0;
                            Hin[(size_t)m * Hn + n] = 0.0f;
                        }
                    }
                }
            }
    } else {  // PHASE 4 (sorted prefix)
#pragma unroll
        for (int fm = 0; fm < 2; fm++)
#pragma unroll
            for (int r = 0; r < 4; r++) {
                int s = m0 + wm * 32 + fm * 16 + (lane >> 4) * 4 + r;
                int alive = (s < cnt);
                int m = perm[s];
                int cch = m >> 3, bb = m & 7;
                int t = cch * Cn + j;
                size_t ob = ((size_t)bb * Tn + t) * (size_t)Hn;
                size_t sb = (size_t)s * Hn;
#pragma unroll
                for (int fn = 0; fn < 2; fn++) {
                    int n = n0 + wn * 32 + fn * 16 + (lane & 15);
                    if (alive) {
                        float val = acc[fm][fn][r];
                        unsigned short h1, h2;
                        split2f(val, h1, h2);
                        O0[sb + n] = h1; O1[sb + n] = h2;
                        Out[ob + n] += val;
                    }
                }
            }
    }
}

// ---------------------------------------------------------------------------
// Exact fallback for uncut chunks (E[occurrences] ~ 0.016).
// ---------------------------------------------------------------------------
__global__ __launch_bounds__(1024) void k_fallback(float* __restrict__ Hin,
                                                   const float* __restrict__ A,
                                                   const int* __restrict__ cut,
                                                   const int* __restrict__ anyUncut,
                                                   unsigned short* __restrict__ u1,
                                                   unsigned short* __restrict__ u2,
                                                   const int* __restrict__ iperm) {
    if (*anyUncut == 0) return;
    __shared__ float v0[Hn];
    __shared__ float v1[Hn];
    for (int c = 1; c < NCn; c++) {
        for (int b = 0; b < Bn; b++) {
            if (cut[(c - 1) * Bn + b]) continue;
            for (int n = threadIdx.x; n < Hn; n += 1024)
                v0[n] = Hin[((size_t)(c - 1) * Bn + b) * Hn + n];
            __syncthreads();
            for (int s = 0; s < Cn; s++) {
                float* pin = (s & 1) ? v1 : v0;
                float* pout = (s & 1) ? v0 : v1;
                for (int n = threadIdx.x; n < Hn; n += 1024) {
                    float accv = 0.0f;
                    const float* Ar = &A[(size_t)n * Hn];
                    for (int k = 0; k < Hn; k++) accv += pin[k] * Ar[k];
                    pout[n] = accv;
                }
                __syncthreads();
            }
            float* pres = (Cn & 1) ? v1 : v0;
            int mrow = c * Bn + b;
            size_t dst = (size_t)mrow * Hn;
            size_t sdst = (size_t)iperm[mrow] * Hn;
            for (int n = threadIdx.x; n < Hn; n += 1024) {
                float nv = Hin[dst + n] + pres[n];
                Hin[dst + n] = nv;
                unsigned short h1, h2;
                split2f(nv, h1, h2);
                u1[sdst + n] = h1; u2[sdst + n] = h2;
            }
            __syncthreads();
        }
    }
}

extern "C" void kernel_launch(void* const* d_in, const int* in_sizes, int n_in,
                              void* d_out, int out_size, void* d_ws, size_t ws_size,
                              hipStream_t stream) {
    const float* x = (const float*)d_in[0];
    const unsigned int* rst = (const unsigned int*)d_in[1];
    const float* Am = (const float*)d_in[2];
    const float* Bm = (const float*)d_in[3];
    float* Out = (float*)d_out;
    char* ws = (char*)d_ws;

    unsigned char* r8 = (unsigned char*)ws;                 // 16 KB
    int* cut = (int*)(ws + 16384);
    int* firstReset = (int*)(ws + 20480);
    int* perm = (int*)(ws + 24576);
    int* iperm = (int*)(ws + 28672);
    int* counts = (int*)(ws + 32768);
    int* anyUncut = (int*)(ws + 32832);
    unsigned short* a1 = (unsigned short*)(ws + 65536);     // A splits [n][k], 8MB ea
    unsigned short* a2 = a1 + 4194304;
    unsigned short* b1 = a2 + 4194304;                      // Bt splits [n][k], 8MB ea
    unsigned short* b2 = b1 + 4194304;
    unsigned short* sP1 = b2 + 4194304;                     // state splits, 4MB ea
    unsigned short* sP2 = sP1 + 2097152;
    unsigned short* sQ1 = sP2 + 2097152;
    unsigned short* sQ2 = sQ1 + 2097152;
    unsigned short* uP1 = sQ2 + 2097152;                    // carry u splits, 4MB ea
    unsigned short* uP2 = uP1 + 2097152;
    float* Hin = (float*)(uP2 + 2097152);                   // 8MB fp32
    unsigned short* x1 = (unsigned short*)(Hin + 2097152);  // X splits, 67MB ea
    unsigned short* x2 = x1 + 33554432;
    const size_t NEED_X = 201392128ull;
    const bool prex = (ws_size >= NEED_X);

    // Mega-prep: A/Bt splits + reset sort (+ X split when prex)
    int prep_grid = prex ? (5121 + 32768) : 5121;
    k_prep<<<prep_grid, 256, 0, stream>>>(Am, a1, a2, Bm, b1, b2,
                                          x, x1, x2, rst, r8, cut, firstReset,
                                          anyUncut, perm, iperm, counts);

    // Phase 1: bx = x @ B  (fused step0 -> sP)
    if (prex) {
        k_gemm_p1<1><<<dim3(Hn / 128, (Bn * Tn) / 256), 512, 0, stream>>>(
            x1, x2, b1, b2, nullptr, Out, sP1, sP2);
    } else {
        k_gemm_p1<0><<<dim3(Hn / 128, (Bn * Tn) / 256), 512, 0, stream>>>(
            nullptr, nullptr, b1, b2, x, Out, sP1, sP2);
    }

    // Phase 2: chunk-local scans (j=15 carries h_in into uP/Hin, zeroes c0)
    for (int j = 1; j < Cn; j++) {
        const unsigned short* i1 = (j & 1) ? sP1 : sQ1;
        const unsigned short* i2 = (j & 1) ? sP2 : sQ2;
        unsigned short* o1 = (j & 1) ? sQ1 : sP1;
        unsigned short* o2 = (j & 1) ? sQ2 : sP2;
        if (j < Cn - 1) {
            k_gemm_s<2><<<dim3(Hn / 64, M2n / 64), 256, 0, stream>>>(
                i1, i2, a1, a2, Out, o1, o2, r8, nullptr, nullptr, nullptr,
                nullptr, nullptr, nullptr, j);
        } else {
            k_gemm_s<3><<<dim3(Hn / 64, M2n / 64), 256, 0, stream>>>(
                i1, i2, a1, a2, Out, o1, o2, r8, nullptr, iperm, nullptr,
                uP1, uP2, Hin, j);
        }
    }

    // Phase 3: exact fallback for uncut chunks
    k_fallback<<<1, 1024, 0, stream>>>(Hin, Am, cut, anyUncut, uP1, uP2, iperm);

    // Phase 4: corrections on shrinking sorted prefix
    for (int j = 0; j < Cn; j++) {
        const unsigned short* i1 = (j == 0) ? uP1 : ((j & 1) ? sP1 : sQ1);
        const unsigned short* i2 = (j == 0) ? uP2 : ((j & 1) ? sP2 : sQ2);
        unsigned short* o1 = (j & 1) ? sQ1 : sP1;
        unsigned short* o2 = (j & 1) ? sQ2 : sP2;
        k_gemm_s<4><<<dim3(Hn / 64, M2n / 64), 256, 0, stream>>>(
            i1, i2, a1, a2, Out, o1, o2, nullptr, perm, nullptr, counts,
            nullptr, nullptr, nullptr, j);
    }
}